// Round 2
// baseline (285.731 us; speedup 1.0000x reference)
//
#include <hip/hip_runtime.h>

// ---------------------------------------------------------------------------
// AgglutinativeAttention: hs->QKV proj -> morpho-biased softmax attn -> out proj
// B=4 S=1024 H=1024 NH=16 HD=64.  bf16 MFMA throughout.
// R10: R9's 256x256 phase-split QKV GEMM kept byte-identical in the K-loop;
//      epilogue rebuilt as LDS-staged coalesced stores. R9 regressed because
//      the 8B scattered epilogue stores stopped being combined in L2:
//      WRITE_SIZE 212MB vs 24MB ideal (8.8x = 64B line / 8B store), adding
//      ~60us of HBM write+RMW traffic. Now each wave transposes its output
//      tile through its private 16KB LDS region (dead after the K-loop) and
//      stores 1KB contiguous per instruction (u16x8 per lane) -> full-line
//      writes by construction. Numerics bit-identical.
// ---------------------------------------------------------------------------

#define QSCALE 0.18033688011112042f   /* 0.125 * log2(e) */
#define CB0    1.0820212806667225f    /* 0.75 * log2(e) */
#define CB1    0.5193702147200268f    /* 0.36 * log2(e) */
#define VERB2  2.8853900817779268f    /* 2.0  * log2(e) */

typedef float  f32x4   __attribute__((ext_vector_type(4)));
typedef short  s16x8   __attribute__((ext_vector_type(8)));
typedef unsigned short u16x4 __attribute__((ext_vector_type(4)));
typedef unsigned short u16x8 __attribute__((ext_vector_type(8)));

#if __has_builtin(__builtin_amdgcn_exp2f)
#define EXP2F(x) __builtin_amdgcn_exp2f(x)
#else
#define EXP2F(x) exp2f(x)
#endif

__device__ __forceinline__ unsigned short f2bf(float f) {
  union { float f; unsigned u; } a; a.f = f;
  unsigned r = a.u + 0x7fffu + ((a.u >> 16) & 1u);   // RNE
  return (unsigned short)(r >> 16);
}

__device__ __forceinline__ void async16(const void* g, void* l) {
  __builtin_amdgcn_global_load_lds(
      (const __attribute__((address_space(1))) unsigned int*)g,
      (__attribute__((address_space(3))) unsigned int*)l, 16, 0, 0);
}

// ---------------- fused prep: cvt (2048) | weight-T x4 (1024) | bias (16) ---
__global__ __launch_bounds__(256) void k_prep(
    const float* __restrict__ hs, unsigned short* __restrict__ hsb,
    const float* __restrict__ Wq, const float* __restrict__ Wk,
    const float* __restrict__ Wv, const float* __restrict__ Wo,
    unsigned short* __restrict__ Wt, const int* __restrict__ mt,
    float* __restrict__ colbias, int* __restrict__ nearest) {
  __shared__ float t[64 * 68];
  int bx = blockIdx.x, tid = threadIdx.x;
  if (bx < 2048) {
    int i = (bx * 256 + tid) * 8;
    float4 v0 = *(const float4*)(hs + i);
    float4 v1 = *(const float4*)(hs + i + 4);
    u16x8 o;
    o[0] = f2bf(v0.x); o[1] = f2bf(v0.y); o[2] = f2bf(v0.z); o[3] = f2bf(v0.w);
    o[4] = f2bf(v1.x); o[5] = f2bf(v1.y); o[6] = f2bf(v1.z); o[7] = f2bf(v1.w);
    *(u16x8*)(hsb + i) = o;
  } else if (bx < 3072) {
    int w = (bx - 2048) >> 8, tt = (bx - 2048) & 255;
    const float* W = (w == 0) ? Wq : (w == 1) ? Wk : (w == 2) ? Wv : Wo;
    unsigned short* Wd = Wt + (size_t)w * 1048576;
    int n0 = (tt & 15) * 64, k0 = (tt >> 4) * 64;
    int r = tid >> 2, c0 = (tid & 3) * 16;
    const float* src = &W[(k0 + r) * 1024 + n0 + c0];
    float4 a0 = *(const float4*)(src + 0);
    float4 a1 = *(const float4*)(src + 4);
    float4 a2 = *(const float4*)(src + 8);
    float4 a3 = *(const float4*)(src + 12);
    *(float4*)&t[r * 68 + c0 + 0]  = a0;
    *(float4*)&t[r * 68 + c0 + 4]  = a1;
    *(float4*)&t[r * 68 + c0 + 8]  = a2;
    *(float4*)&t[r * 68 + c0 + 12] = a3;
    __syncthreads();
    u16x8 o0, o1;
#pragma unroll
    for (int j = 0; j < 8; j++) {
      o0[j] = f2bf(t[(c0 + j) * 68 + r]);
      o1[j] = f2bf(t[(c0 + 8 + j) * 68 + r]);
    }
    *(u16x8*)&Wd[(n0 + r) * 1024 + k0 + c0]     = o0;
    *(u16x8*)&Wd[(n0 + r) * 1024 + k0 + c0 + 8] = o1;
  } else {
    int i = bx - 3072;
    int b = i >> 2;
    int* sm = (int*)t;
    for (int j = tid; j < 1024; j += 256) sm[j] = mt[b * 1024 + j];
    __syncthreads();
    int q = (i & 3) * 256 + tid;
    int best = 1 << 30, bj = -1;
    for (int j = 0; j < 1024; ++j) {
      int d = (q > j) ? (q - j) : (j - q);
      int dd = (sm[j] == 2) ? d : (1 << 30);
      if (dd < best) { best = dd; bj = j; }
    }
    nearest[b * 1024 + q] = bj;
    int m = sm[q];
    colbias[b * 1024 + q] = CB0 * (m == 0) + CB1 * (m == 1);
  }
}

// ---------------- out-proj GEMM (MODE 1 only), BK=64, XOR-swizzled ----------
template <int MODE>
__global__ __launch_bounds__(256) void k_gemm(
    const unsigned short* __restrict__ A,
    const unsigned short* __restrict__ WtBase,
    const float* __restrict__ bias0, const float* __restrict__ bias1,
    const float* __restrict__ bias2,
    unsigned short* __restrict__ outB, unsigned short* __restrict__ outV,
    float* __restrict__ outF) {
  constexpr int TM = (MODE == 0) ? 128 : 64;
  constexpr int NI = (MODE == 0) ? 4 : 2;       // m-fragments per wave
  constexpr int RA = TM / 4;                    // A rows staged per wave
  __shared__ unsigned short As[TM * 64];
  __shared__ unsigned short Bs[128 * 64];
  int tid = threadIdx.x, wid = tid >> 6, lane = tid & 63;
  int c = lane & 15, quad = lane >> 4;
  int m0, wsel, n0;
  const unsigned short* Bt;
  const float* bias;
  if (MODE == 0) {
    wsel = blockIdx.x >> 3;
    n0 = (blockIdx.x & 7) * 128;
    m0 = blockIdx.y * 128;
    Bt = WtBase + wsel * 1048576;
    bias = (wsel == 0) ? bias0 : ((wsel == 1) ? bias1 : bias2);
  } else {
    wsel = 0;
    n0 = blockIdx.x * 128;
    m0 = blockIdx.y * 64;
    Bt = WtBase; bias = bias0;
  }
  int wm = (wid >> 1) * (16 * NI), wn = (wid & 1) * 64;
  int lr = lane >> 3, lc = lane & 7;
  int gcol = ((lc ^ lr) << 3);                  // XOR-swizzled 16B chunk
  const unsigned short* ga = A  + (size_t)(m0 + wid * RA + lr) * 1024 + gcol;
  const unsigned short* gb = Bt + (size_t)(n0 + wid * 32 + lr) * 1024 + gcol;
  unsigned short* lA = &As[(wid * RA) * 64];
  unsigned short* lB = &Bs[(wid * 32) * 64];

  f32x4 acc[NI][4];
#pragma unroll
  for (int i = 0; i < NI; i++)
#pragma unroll
    for (int j = 0; j < 4; j++) acc[i][j] = (f32x4){0.f, 0.f, 0.f, 0.f};

  bool sw = (MODE == 1) || (wsel != 2);         // swapped-operand (wave-uniform)

  for (int k0 = 0; k0 < 1024; k0 += 64) {
#pragma unroll
    for (int i = 0; i < RA / 8; i++) async16(ga + i * 8 * 1024 + k0, lA + i * 8 * 64);
#pragma unroll
    for (int j = 0; j < 4; j++)      async16(gb + j * 8 * 1024 + k0, lB + j * 8 * 64);
    __syncthreads();                             // staging visible (vmcnt drained)
#pragma unroll
    for (int ks = 0; ks < 2; ks++) {
      s16x8 af[NI], bf[4];
#pragma unroll
      for (int i = 0; i < NI; i++)
        af[i] = *(const s16x8*)&As[(wm + i * 16 + c) * 64 + (((ks * 4 + quad) ^ (c & 7)) << 3)];
#pragma unroll
      for (int j = 0; j < 4; j++)
        bf[j] = *(const s16x8*)&Bs[(wn + j * 16 + c) * 64 + (((ks * 4 + quad) ^ (c & 7)) << 3)];
      if (sw) {
#pragma unroll
        for (int i = 0; i < NI; i++)
#pragma unroll
          for (int j = 0; j < 4; j++)
            acc[i][j] = __builtin_amdgcn_mfma_f32_16x16x32_bf16(bf[j], af[i], acc[i][j], 0, 0, 0);
      } else {
#pragma unroll
        for (int i = 0; i < NI; i++)
#pragma unroll
          for (int j = 0; j < 4; j++)
            acc[i][j] = __builtin_amdgcn_mfma_f32_16x16x32_bf16(af[i], bf[j], acc[i][j], 0, 0, 0);
      }
    }
    __syncthreads();                             // all reads done before re-stage
  }

  if (MODE == 1) {
    // swapped: row=feature (4-contig), col=token -> float4 stores
#pragma unroll
    for (int j = 0; j < 4; j++) {
      int colb = n0 + wn + j * 16 + quad * 4;
      f32x4 bvv = *(const f32x4*)&bias[colb];
#pragma unroll
      for (int i = 0; i < NI; i++) {
        int s_tok = m0 + wm + i * 16 + c;
        f32x4 v = acc[i][j] + bvv;
        *(f32x4*)&outF[(size_t)s_tok * 1024 + colb] = v;
      }
    }
  } else if (wsel == 2) {
#pragma unroll
    for (int j = 0; j < 4; j++) {
      int col = n0 + wn + j * 16 + c;
      float bv = bias[col];
      int h = col >> 6, d = col & 63;
#pragma unroll
      for (int i = 0; i < NI; i++) {
        int row = m0 + wm + i * 16 + quad * 4;
        int bb = row >> 10, s = row & 1023;
        u16x4 pk;
#pragma unroll
        for (int r = 0; r < 4; r++) pk[r] = f2bf(acc[i][j][r] + bv);
        *(u16x4*)&outV[(size_t)(((bb * 16 + h) * 64 + d)) * 1024 + s] = pk;
      }
    }
  } else {
    float sc = (wsel == 0) ? QSCALE : 1.0f;
#pragma unroll
    for (int j = 0; j < 4; j++) {
      int colb = n0 + wn + j * 16 + quad * 4;
      f32x4 bvv = *(const f32x4*)&bias[colb];
      int h = colb >> 6, d0 = colb & 63;
#pragma unroll
      for (int i = 0; i < NI; i++) {
        int s_tok = m0 + wm + i * 16 + c;
        int bb = s_tok >> 10, s = s_tok & 1023;
        u16x4 pk;
#pragma unroll
        for (int r = 0; r < 4; r++) pk[r] = f2bf((acc[i][j][r] + bvv[r]) * sc);
        *(u16x4*)&outB[(size_t)wsel * 4194304 + (((bb * 16 + h) * 1024 + s) * 64) + d0] = pk;
      }
    }
  }
}

// ---------------- QKV GEMM: 256x256 tile, 8 waves, phase-split + vmcnt(N) ---
#define QKV_QUAD(AFR, MB, NB)                                                 \
  if (sw) {                                                                   \
    _Pragma("unroll") for (int ks = 0; ks < 2; ks++)                          \
    _Pragma("unroll") for (int mf = 0; mf < 4; mf++)                          \
    _Pragma("unroll") for (int nf = 0; nf < 2; nf++)                          \
      acc[(MB) + mf][(NB) + nf] = __builtin_amdgcn_mfma_f32_16x16x32_bf16(    \
          b[(NB) + nf][ks], AFR[mf][ks], acc[(MB) + mf][(NB) + nf], 0, 0, 0); \
  } else {                                                                    \
    _Pragma("unroll") for (int ks = 0; ks < 2; ks++)                          \
    _Pragma("unroll") for (int mf = 0; mf < 4; mf++)                          \
    _Pragma("unroll") for (int nf = 0; nf < 2; nf++)                          \
      acc[(MB) + mf][(NB) + nf] = __builtin_amdgcn_mfma_f32_16x16x32_bf16(    \
          AFR[mf][ks], b[(NB) + nf][ks], acc[(MB) + mf][(NB) + nf], 0, 0, 0); \
  }

// One BK=64 K-tile on buffer (Ac,Bc). 4 phases (see R9 comment); vmcnt(8)
// once per K-tile, never 0 in the main loop.
template <bool STAGE, int VMN>
__device__ __forceinline__ void qkv_ktile(
    unsigned short* Ac, unsigned short* Bc,
    const unsigned short* ga, const unsigned short* gb, int k2,
    int wid, int wm, int wn, int c, int quad, bool sw, f32x4 (&acc)[8][4]) {
  const int cs = c & 7;
  s16x8 a0[4][2], a1[4][2], b[4][2];
  // ---- P0
#pragma unroll
  for (int mf = 0; mf < 4; mf++)
#pragma unroll
    for (int ks = 0; ks < 2; ks++)
      a0[mf][ks] = *(const s16x8*)&Ac[(wm * 128 + mf * 16 + c) * 64 + (((ks * 4 + quad) ^ cs) << 3)];
#pragma unroll
  for (int nf = 0; nf < 2; nf++)
#pragma unroll
    for (int ks = 0; ks < 2; ks++)
      b[nf][ks] = *(const s16x8*)&Bc[(wn * 64 + nf * 16 + c) * 64 + (((ks * 4 + quad) ^ cs) << 3)];
  __builtin_amdgcn_s_barrier();
  __asm__ volatile("s_waitcnt lgkmcnt(0)" ::: "memory");
  __builtin_amdgcn_s_setprio(1);
  QKV_QUAD(a0, 0, 0)
  __builtin_amdgcn_s_setprio(0);
  __builtin_amdgcn_s_barrier();
  // ---- P1
#pragma unroll
  for (int nf = 2; nf < 4; nf++)
#pragma unroll
    for (int ks = 0; ks < 2; ks++)
      b[nf][ks] = *(const s16x8*)&Bc[(wn * 64 + nf * 16 + c) * 64 + (((ks * 4 + quad) ^ cs) << 3)];
#pragma unroll
  for (int mf = 0; mf < 4; mf++)
#pragma unroll
    for (int ks = 0; ks < 2; ks++)
      a1[mf][ks] = *(const s16x8*)&Ac[(wm * 128 + 64 + mf * 16 + c) * 64 + (((ks * 4 + quad) ^ cs) << 3)];
  __builtin_amdgcn_s_barrier();
  __asm__ volatile("s_waitcnt lgkmcnt(0)" ::: "memory");   // drains ALL 24 reads
  __builtin_amdgcn_s_setprio(1);
  QKV_QUAD(a0, 0, 2)
  __builtin_amdgcn_s_setprio(0);
  __builtin_amdgcn_s_barrier();                            // licenses re-stage
  // ---- P2
  if constexpr (STAGE) {
#pragma unroll
    for (int j = 0; j < 2; j++) {
      async16(ga + j * 8 * 1024 + k2, Ac + (wid * 32 + j * 8) * 64);
      async16(gb + j * 8 * 1024 + k2, Bc + (wid * 32 + j * 8) * 64);
    }
  }
  __builtin_amdgcn_s_barrier();
  __builtin_amdgcn_s_setprio(1);
  QKV_QUAD(a1, 4, 0)
  __builtin_amdgcn_s_setprio(0);
  __builtin_amdgcn_s_barrier();
  // ---- P3
  if constexpr (STAGE) {
#pragma unroll
    for (int j = 2; j < 4; j++) {
      async16(ga + j * 8 * 1024 + k2, Ac + (wid * 32 + j * 8) * 64);
      async16(gb + j * 8 * 1024 + k2, Bc + (wid * 32 + j * 8) * 64);
    }
  }
  __builtin_amdgcn_s_barrier();
  __builtin_amdgcn_s_setprio(1);
  QKV_QUAD(a1, 4, 2)
  __builtin_amdgcn_s_setprio(0);
  if constexpr (VMN == 8)
    __asm__ volatile("s_waitcnt vmcnt(8)" ::: "memory");
  else if constexpr (VMN == 0)
    __asm__ volatile("s_waitcnt vmcnt(0)" ::: "memory");
  __builtin_amdgcn_s_barrier();
}

// grid (12,16): x = wsel*4 + n-tile, y = m-tile. 512 threads = 8 waves 2Mx4N;
// per-wave output 128x64. LDS 128KB = dbuf (A 256x64 + B 256x64) bf16,
// reused post-loop as 8 x 16KB per-wave transpose buffers for the epilogue.
__global__ __launch_bounds__(512, 2) void k_qkv256(
    const unsigned short* __restrict__ A,
    const unsigned short* __restrict__ WtBase,
    const float* __restrict__ bq, const float* __restrict__ bk,
    const float* __restrict__ bv,
    unsigned short* __restrict__ outQK, unsigned short* __restrict__ outV) {
  __shared__ unsigned short SMEM[65536];        // 128 KB flat
  unsigned short* As0 = SMEM;
  unsigned short* As1 = SMEM + 16384;
  unsigned short* Bs0 = SMEM + 32768;
  unsigned short* Bs1 = SMEM + 49152;
  int tid = threadIdx.x, wid = tid >> 6, lane = tid & 63;
  int c = lane & 15, quad = lane >> 4;
  int wm = wid >> 2, wn = wid & 3;
  int wsel = blockIdx.x >> 2;
  int n0 = (blockIdx.x & 3) * 256;
  int m0 = blockIdx.y * 256;
  const unsigned short* Bt = WtBase + (size_t)wsel * 1048576;
  const float* bias = (wsel == 0) ? bq : ((wsel == 1) ? bk : bv);
  bool sw = (wsel != 2);                         // Q/K swapped-operand

  int lr = lane >> 3, lc = lane & 7;
  int gcol = (lc ^ lr) << 3;                     // XOR-swizzled source chunk
  const unsigned short* ga = A  + (size_t)(m0 + wid * 32 + lr) * 1024 + gcol;
  const unsigned short* gb = Bt + (size_t)(n0 + wid * 32 + lr) * 1024 + gcol;

  f32x4 acc[8][4];
#pragma unroll
  for (int i = 0; i < 8; i++)
#pragma unroll
    for (int j = 0; j < 4; j++) acc[i][j] = (f32x4){0.f, 0.f, 0.f, 0.f};

  // prologue: K-tile 0 -> buf0 (8 loads), K-tile 1 -> buf1 (8 loads)
#pragma unroll
  for (int j = 0; j < 4; j++) {
    async16(ga + j * 8 * 1024,      As0 + (wid * 32 + j * 8) * 64);
    async16(gb + j * 8 * 1024,      Bs0 + (wid * 32 + j * 8) * 64);
  }
#pragma unroll
  for (int j = 0; j < 4; j++) {
    async16(ga + j * 8 * 1024 + 64, As1 + (wid * 32 + j * 8) * 64);
    async16(gb + j * 8 * 1024 + 64, Bs1 + (wid * 32 + j * 8) * 64);
  }
  __asm__ volatile("s_waitcnt vmcnt(8)" ::: "memory");   // K-tile 0 landed
  __builtin_amdgcn_s_barrier();

  for (int kt = 0; kt < 14; kt += 2) {
    qkv_ktile<true, 8>(As0, Bs0, ga, gb, (kt + 2) * 64,
                       wid, wm, wn, c, quad, sw, acc);
    qkv_ktile<true, 8>(As1, Bs1, ga, gb, (kt + 3) * 64,
                       wid, wm, wn, c, quad, sw, acc);
  }
  qkv_ktile<false, 0>(As0, Bs0, ga, gb, 0, wid, wm, wn, c, quad, sw, acc);
  qkv_ktile<false, -1>(As1, Bs1, ga, gb, 0, wid, wm, wn, c, quad, sw, acc);
  // final s_barrier done inside; all K-loop LDS reads drained -> LDS reusable.

  // ---- epilogue: per-wave LDS transpose -> full-line coalesced stores ----
  unsigned short* W = SMEM + wid * 8192;         // private 16KB per wave
  int tokbase = m0 + wm * 128;
  int bb = tokbase >> 10, s0 = tokbase & 1023;   // 128-aligned, single b
  int h = (n0 + wn * 64) >> 6;

  if (!sw) {
    // V: value(tok = mf*16+quad*4+r, d = nf*16+c). LDS [d][128 tok] bf16,
    // 256B rows = 16 chunks of 16B, chunk-swizzled by (d&15).
#pragma unroll
    for (int nf = 0; nf < 4; nf++) {
      int col = n0 + wn * 64 + nf * 16 + c;
      float bvv = bias[col];
      int d = nf * 16 + c;                       // local d, 0..63
#pragma unroll
      for (int mf = 0; mf < 8; mf++) {
        u16x4 pk;
#pragma unroll
        for (int r = 0; r < 4; r++) pk[r] = f2bf(acc[mf][nf][r] + bvv);
        int ch = mf * 2 + (quad >> 1);           // 16B chunk 0..15
        int chs = ch ^ c;                        // swizzle by (d&15)==c
        *(u16x4*)&W[d * 128 + chs * 8 + (quad & 1) * 4] = pk;
      }
    }
    __asm__ volatile("s_waitcnt lgkmcnt(0)" ::: "memory");
    int r16 = lane >> 4, chl = lane & 15;
    unsigned short* gw = outV + ((size_t)(bb * 16 + h) * 64) * 1024 + s0;
#pragma unroll
    for (int t = 0; t < 16; t++) {
      int d = t * 4 + r16;
      int chs = chl ^ (d & 15);
      u16x8 vv = *(const u16x8*)&W[d * 128 + chs * 8];
      *(u16x8*)&gw[(size_t)d * 1024 + chl * 8] = vv;  // 4x256B lines/instr
    }
  } else {
    // Q/K: value(tok = mf*16+c, d = nf*16+quad*4+r). LDS [tok][64 d] bf16,
    // 128B rows = 8 chunks of 16B, chunk-swizzled by (tok&7).
    float sc = (wsel == 0) ? QSCALE : 1.0f;
#pragma unroll
    for (int nf = 0; nf < 4; nf++) {
      int colb = n0 + wn * 64 + nf * 16 + quad * 4;
      f32x4 bvv = *(const f32x4*)&bias[colb];
#pragma unroll
      for (int mf = 0; mf < 8; mf++) {
        u16x4 pk;
#pragma unroll
        for (int r = 0; r < 4; r++) pk[r] = f2bf((acc[mf][nf][r] + bvv[r]) * sc);
        int tok = mf * 16 + c;                   // local token, 0..127
        int ch = nf * 2 + (quad >> 1);           // 16B chunk 0..7
        int chs = ch ^ (tok & 7);
        *(u16x4*)&W[tok * 64 + chs * 8 + (quad & 1) * 4] = pk;
      }
    }
    __asm__ volatile("s_waitcnt lgkmcnt(0)" ::: "memory");
    int r8 = lane >> 3, chl = lane & 7;
    unsigned short* outp = outQK + (size_t)wsel * 4194304;
    unsigned short* gw = outp + ((size_t)(bb * 16 + h) * 1024 + s0) * 64;
#pragma unroll
    for (int t = 0; t < 16; t++) {
      int tok = t * 8 + r8;
      int chs = chl ^ (tok & 7);
      u16x8 vv = *(const u16x8*)&W[tok * 64 + chs * 8];
      *(u16x8*)&gw[tok * 64 + chl * 8] = vv;     // 1KB contiguous/instr
    }
  }
}

// ---------------- Flash attention, 16x16x32 MFMA, streaming softmax ---------
__global__ __launch_bounds__(256) void k_attn(
    const unsigned short* __restrict__ Q, const unsigned short* __restrict__ K,
    const unsigned short* __restrict__ Vt, const float* __restrict__ colbias,
    const int* __restrict__ nearest, unsigned short* __restrict__ AO) {
  __shared__ unsigned short Ks[64 * 72];     // [key][d]
  __shared__ unsigned short Vs[64 * 72];     // [d][key]
  __shared__ unsigned short Ps[4][32 * 72];  // per-wave [q][key]
  __shared__ float Cb[1024];
  int tid = threadIdx.x, wid = tid >> 6, lane = tid & 63;
  int c = lane & 15, quad = lane >> 4;
  int bh = blockIdx.x, qt = blockIdx.y;
  int b = bh >> 4, head = bh & 15;
  int q0 = qt * 128, wq = wid * 32;
  const unsigned short* Qg = Q  + (size_t)(bh * 1024 + q0 + wq) * 64;
  const unsigned short* Kg = K  + (size_t)bh * 1024 * 64;
  const unsigned short* Vg = Vt + (size_t)bh * 64 * 1024;

  *(float4*)&Cb[tid * 4] = *(const float4*)&colbias[b * 1024 + tid * 4];

  s16x8 qf[2][2];
#pragma unroll
  for (int nt = 0; nt < 2; nt++)
#pragma unroll
    for (int ks = 0; ks < 2; ks++)
      qf[nt][ks] = *(const s16x8*)&Qg[(nt * 16 + c) * 64 + ks * 32 + quad * 8];

  int nq[2];
  nq[0] = nearest[b * 1024 + q0 + wq + c];
  nq[1] = nearest[b * 1024 + q0 + wq + 16 + c];

  f32x4 o[2][4];
#pragma unroll
  for (int i = 0; i < 2; i++)
#pragma unroll
    for (int j = 0; j < 4; j++) o[i][j] = (f32x4){0.f, 0.f, 0.f, 0.f};
  float lrun[2] = {0.f, 0.f};

  int srow = tid >> 3, scol8 = (tid & 7) * 8;

  u16x8 kr[2], vr[2];
#pragma unroll
  for (int it = 0; it < 2; ++it) {
    int r2 = it * 32 + srow;
    kr[it] = *(const u16x8*)&Kg[r2 * 64 + scol8];
    vr[it] = *(const u16x8*)&Vg[r2 * 1024 + scol8];
  }
  __syncthreads();   // Cb visible before first use

  for (int kc = 0; kc < 16; ++kc) {
#pragma unroll
    for (int it = 0; it < 2; ++it) {
      int r2 = it * 32 + srow;
      *(u16x8*)&Ks[r2 * 72 + scol8] = kr[it];
      *(u16x8*)&Vs[r2 * 72 + scol8] = vr[it];
    }
    __syncthreads();
    if (kc < 15) {
#pragma unroll
      for (int it = 0; it < 2; ++it) {
        int r2 = it * 32 + srow;
        kr[it] = *(const u16x8*)&Kg[((kc + 1) * 64 + r2) * 64 + scol8];
        vr[it] = *(const u16x8*)&Vg[r2 * 1024 + (kc + 1) * 64 + scol8];
      }
    }

    // S^T = K . Q^T : st[mt][nt] (key = mt*16+quad*4+r, q = nt*16+c)
    f32x4 st[4][2];
#pragma unroll
    for (int mt = 0; mt < 4; mt++)
#pragma unroll
      for (int nt = 0; nt < 2; nt++) st[mt][nt] = (f32x4){0.f, 0.f, 0.f, 0.f};
#pragma unroll
    for (int mt = 0; mt < 4; mt++)
#pragma unroll
      for (int ks = 0; ks < 2; ks++) {
        s16x8 a = *(const s16x8*)&Ks[(mt * 16 + c) * 72 + ks * 32 + quad * 8];
#pragma unroll
        for (int nt = 0; nt < 2; nt++)
          st[mt][nt] = __builtin_amdgcn_mfma_f32_16x16x32_bf16(a, qf[nt][ks], st[mt][nt], 0, 0, 0);
      }

    // rare verb-bias fixup: nq lands in this chunk for at most one element
    bool h0 = (nq[0] >> 6) == kc;
    bool h1 = (nq[1] >> 6) == kc;
    if (__any(h0 || h1)) {
#pragma unroll
      for (int mt = 0; mt < 4; mt++)
#pragma unroll
        for (int nt = 0; nt < 2; nt++)
#pragma unroll
          for (int r = 0; r < 4; r++)
            if (kc * 64 + mt * 16 + quad * 4 + r == nq[nt]) st[mt][nt][r] += VERB2;
    }

    // hot path: cb add + exp2 + v_perm truncate-pack; l from packed values
#pragma unroll
    for (int mt = 0; mt < 4; mt++) {
      f32x4 cb = *(const f32x4*)&Cb[kc * 64 + mt * 16 + quad * 4];
#pragma unroll
      for (int nt = 0; nt < 2; nt++) {
        float e0 = EXP2F(st[mt][nt][0] + cb[0]);
        float e1 = EXP2F(st[mt][nt][1] + cb[1]);
        float e2 = EXP2F(st[mt][nt][2] + cb[2]);
        float e3 = EXP2F(st[mt][nt][3] + cb[3]);
        unsigned p01 = __builtin_amdgcn_perm(__float_as_uint(e1), __float_as_uint(e0), 0x07060302u);
        unsigned p23 = __builtin_amdgcn_perm(__float_as_uint(e3), __float_as_uint(e2), 0x07060302u);
        lrun[nt] += __uint_as_float(p01 << 16) + __uint_as_float(p01 & 0xffff0000u)
                  + __uint_as_float(p23 << 16) + __uint_as_float(p23 & 0xffff0000u);
        uint2 pk; pk.x = p01; pk.y = p23;
        *(uint2*)&Ps[wid][(nt * 16 + c) * 72 + mt * 16 + quad * 4] = pk;
      }
    }
    __asm__ volatile("s_waitcnt lgkmcnt(0)" ::: "memory");

    // O += (P . V) computed SWAPPED: o[mtq][ntd] rows = d, cols = q
#pragma unroll
    for (int ks = 0; ks < 2; ks++) {
      s16x8 pa[2];
#pragma unroll
      for (int mtq = 0; mtq < 2; mtq++)
        pa[mtq] = *(const s16x8*)&Ps[wid][(mtq * 16 + c) * 72 + ks * 32 + quad * 8];
#pragma unroll
      for (int ntd = 0; ntd < 4; ntd++) {
        s16x8 vb = *(const s16x8*)&Vs[(ntd * 16 + c) * 72 + ks * 32 + quad * 8];
#pragma unroll
        for (int mtq = 0; mtq < 2; mtq++)
          o[mtq][ntd] = __builtin_amdgcn_mfma_f32_16x16x32_bf16(vb, pa[mtq], o[mtq][ntd], 0, 0, 0);
      }
    }
    __syncthreads();
  }

  // l-reduction across quads; lane's own token = mtq*16+c -> no shuffle
#pragma unroll
  for (int nt = 0; nt < 2; nt++) {
    lrun[nt] += __shfl_xor(lrun[nt], 16, 64);
    lrun[nt] += __shfl_xor(lrun[nt], 32, 64);
  }
  float linv[2] = {1.0f / lrun[0], 1.0f / lrun[1]};
#pragma unroll
  for (int mtq = 0; mtq < 2; mtq++) {
    size_t row = (size_t)(b * 1024 + q0 + wq + mtq * 16 + c);
#pragma unroll
    for (int ntd = 0; ntd < 4; ntd++) {
      int d0 = ntd * 16 + quad * 4;
      u16x4 pk;
#pragma unroll
      for (int r = 0; r < 4; r++) pk[r] = f2bf(o[mtq][ntd][r] * linv[mtq]);
      *(u16x4*)&AO[row * 1024 + head * 64 + d0] = pk;
    }
  }
}

// ---------------------------------------------------------------------------
extern "C" void kernel_launch(void* const* d_in, const int* in_sizes, int n_in,
                              void* d_out, int out_size, void* d_ws, size_t ws_size,
                              hipStream_t stream) {
  const float* hs     = (const float*)d_in[0];
  const int*   morpho = (const int*)d_in[1];
  const float* Wq = (const float*)d_in[2];
  const float* bq = (const float*)d_in[3];
  const float* Wk = (const float*)d_in[4];
  const float* bk = (const float*)d_in[5];
  const float* Wv = (const float*)d_in[6];
  const float* bv = (const float*)d_in[7];
  const float* Wo = (const float*)d_in[8];
  const float* bo = (const float*)d_in[9];
  float* out = (float*)d_out;

  char* ws = (char*)d_ws;
  unsigned short* hsb = (unsigned short*)(ws);                    // 8 MB [4096][1024]
  unsigned short* Wt  = (unsigned short*)(ws + (8u << 20));       // 8 MB [4][1024][1024]
  unsigned short* Qb  = (unsigned short*)(ws + (16u << 20));      // Q +16MB, K +24MB
  unsigned short* Kb  = (unsigned short*)(ws + (24u << 20));
  unsigned short* Vtb = (unsigned short*)(ws + (40u << 20));      // 8 MB [B,NH,HD,S]
  float* colbias      = (float*)(ws + (48u << 20));               // 16 KB
  int*   nearestp     = (int*)(ws + (48u << 20) + (16u << 10));   // 16 KB
  unsigned short* AO  = hsb;  // reuse: hs_bf16 dead after QKV GEMM

  k_prep<<<3088, 256, 0, stream>>>(hs, hsb, Wq, Wk, Wv, Wo, Wt, morpho,
                                   colbias, nearestp);
  k_qkv256<<<dim3(12, 16), 512, 0, stream>>>(hsb, Wt, bq, bk, bv, Qb, Vtb);
  k_attn<<<dim3(64, 8), 256, 0, stream>>>(Qb, Kb, Vtb, colbias, nearestp, AO);
  k_gemm<1><<<dim3(8, 64), 256, 0, stream>>>(AO, Wt + 3 * 1048576, bo, nullptr, nullptr,
                                             nullptr, nullptr, out);
  (void)in_sizes; (void)n_in; (void)out_size; (void)ws_size; (void)Kb;
}

// Round 3
// 282.738 us; speedup vs baseline: 1.0106x; 1.0106x over previous
//
#include <hip/hip_runtime.h>

// ---------------------------------------------------------------------------
// AgglutinativeAttention: hs->QKV proj -> morpho-biased softmax attn -> out proj
// B=4 S=1024 H=1024 NH=16 HD=64.  bf16 MFMA throughout.
// R11: spill fix for the 256x256 QKV GEMM. R9/R10's 207-212MB WRITE_SIZE was
//      VGPR spill-to-scratch, not store scatter: __launch_bounds__(512,2)
//      capped the allocator at 128 regs (VGPR_Count=128 observed) while the
//      K-loop needs ~240 (acc 128 + frags + addr). Changes:
//      (a) __launch_bounds__(512,1) -> ~256-reg budget, 2 waves/SIMD;
//      (b) quadrant order (a0,b01)(a1,b01)(a1,b23)(a0,b23) with per-phase
//          fragment loads -> frag live-set 96 -> ~80 peak. Barrier protocol:
//          A-reads drain by P1's lgkm0 -> A-staging in P2; B-reads drain by
//          P2's lgkm0 -> B-staging in P3; vmcnt(8) once per K-tile.
//      R10's full-line LDS-transpose epilogue kept (writes 25MB ideal).
// ---------------------------------------------------------------------------

#define QSCALE 0.18033688011112042f   /* 0.125 * log2(e) */
#define CB0    1.0820212806667225f    /* 0.75 * log2(e) */
#define CB1    0.5193702147200268f    /* 0.36 * log2(e) */
#define VERB2  2.8853900817779268f    /* 2.0  * log2(e) */

typedef float  f32x4   __attribute__((ext_vector_type(4)));
typedef short  s16x8   __attribute__((ext_vector_type(8)));
typedef unsigned short u16x4 __attribute__((ext_vector_type(4)));
typedef unsigned short u16x8 __attribute__((ext_vector_type(8)));

#if __has_builtin(__builtin_amdgcn_exp2f)
#define EXP2F(x) __builtin_amdgcn_exp2f(x)
#else
#define EXP2F(x) exp2f(x)
#endif

__device__ __forceinline__ unsigned short f2bf(float f) {
  union { float f; unsigned u; } a; a.f = f;
  unsigned r = a.u + 0x7fffu + ((a.u >> 16) & 1u);   // RNE
  return (unsigned short)(r >> 16);
}

__device__ __forceinline__ void async16(const void* g, void* l) {
  __builtin_amdgcn_global_load_lds(
      (const __attribute__((address_space(1))) unsigned int*)g,
      (__attribute__((address_space(3))) unsigned int*)l, 16, 0, 0);
}

// ---------------- fused prep: cvt (2048) | weight-T x4 (1024) | bias (16) ---
__global__ __launch_bounds__(256) void k_prep(
    const float* __restrict__ hs, unsigned short* __restrict__ hsb,
    const float* __restrict__ Wq, const float* __restrict__ Wk,
    const float* __restrict__ Wv, const float* __restrict__ Wo,
    unsigned short* __restrict__ Wt, const int* __restrict__ mt,
    float* __restrict__ colbias, int* __restrict__ nearest) {
  __shared__ float t[64 * 68];
  int bx = blockIdx.x, tid = threadIdx.x;
  if (bx < 2048) {
    int i = (bx * 256 + tid) * 8;
    float4 v0 = *(const float4*)(hs + i);
    float4 v1 = *(const float4*)(hs + i + 4);
    u16x8 o;
    o[0] = f2bf(v0.x); o[1] = f2bf(v0.y); o[2] = f2bf(v0.z); o[3] = f2bf(v0.w);
    o[4] = f2bf(v1.x); o[5] = f2bf(v1.y); o[6] = f2bf(v1.z); o[7] = f2bf(v1.w);
    *(u16x8*)(hsb + i) = o;
  } else if (bx < 3072) {
    int w = (bx - 2048) >> 8, tt = (bx - 2048) & 255;
    const float* W = (w == 0) ? Wq : (w == 1) ? Wk : (w == 2) ? Wv : Wo;
    unsigned short* Wd = Wt + (size_t)w * 1048576;
    int n0 = (tt & 15) * 64, k0 = (tt >> 4) * 64;
    int r = tid >> 2, c0 = (tid & 3) * 16;
    const float* src = &W[(k0 + r) * 1024 + n0 + c0];
    float4 a0 = *(const float4*)(src + 0);
    float4 a1 = *(const float4*)(src + 4);
    float4 a2 = *(const float4*)(src + 8);
    float4 a3 = *(const float4*)(src + 12);
    *(float4*)&t[r * 68 + c0 + 0]  = a0;
    *(float4*)&t[r * 68 + c0 + 4]  = a1;
    *(float4*)&t[r * 68 + c0 + 8]  = a2;
    *(float4*)&t[r * 68 + c0 + 12] = a3;
    __syncthreads();
    u16x8 o0, o1;
#pragma unroll
    for (int j = 0; j < 8; j++) {
      o0[j] = f2bf(t[(c0 + j) * 68 + r]);
      o1[j] = f2bf(t[(c0 + 8 + j) * 68 + r]);
    }
    *(u16x8*)&Wd[(n0 + r) * 1024 + k0 + c0]     = o0;
    *(u16x8*)&Wd[(n0 + r) * 1024 + k0 + c0 + 8] = o1;
  } else {
    int i = bx - 3072;
    int b = i >> 2;
    int* sm = (int*)t;
    for (int j = tid; j < 1024; j += 256) sm[j] = mt[b * 1024 + j];
    __syncthreads();
    int q = (i & 3) * 256 + tid;
    int best = 1 << 30, bj = -1;
    for (int j = 0; j < 1024; ++j) {
      int d = (q > j) ? (q - j) : (j - q);
      int dd = (sm[j] == 2) ? d : (1 << 30);
      if (dd < best) { best = dd; bj = j; }
    }
    nearest[b * 1024 + q] = bj;
    int m = sm[q];
    colbias[b * 1024 + q] = CB0 * (m == 0) + CB1 * (m == 1);
  }
}

// ---------------- out-proj GEMM (MODE 1 only), BK=64, XOR-swizzled ----------
template <int MODE>
__global__ __launch_bounds__(256) void k_gemm(
    const unsigned short* __restrict__ A,
    const unsigned short* __restrict__ WtBase,
    const float* __restrict__ bias0, const float* __restrict__ bias1,
    const float* __restrict__ bias2,
    unsigned short* __restrict__ outB, unsigned short* __restrict__ outV,
    float* __restrict__ outF) {
  constexpr int TM = (MODE == 0) ? 128 : 64;
  constexpr int NI = (MODE == 0) ? 4 : 2;       // m-fragments per wave
  constexpr int RA = TM / 4;                    // A rows staged per wave
  __shared__ unsigned short As[TM * 64];
  __shared__ unsigned short Bs[128 * 64];
  int tid = threadIdx.x, wid = tid >> 6, lane = tid & 63;
  int c = lane & 15, quad = lane >> 4;
  int m0, wsel, n0;
  const unsigned short* Bt;
  const float* bias;
  if (MODE == 0) {
    wsel = blockIdx.x >> 3;
    n0 = (blockIdx.x & 7) * 128;
    m0 = blockIdx.y * 128;
    Bt = WtBase + wsel * 1048576;
    bias = (wsel == 0) ? bias0 : ((wsel == 1) ? bias1 : bias2);
  } else {
    wsel = 0;
    n0 = blockIdx.x * 128;
    m0 = blockIdx.y * 64;
    Bt = WtBase; bias = bias0;
  }
  int wm = (wid >> 1) * (16 * NI), wn = (wid & 1) * 64;
  int lr = lane >> 3, lc = lane & 7;
  int gcol = ((lc ^ lr) << 3);                  // XOR-swizzled 16B chunk
  const unsigned short* ga = A  + (size_t)(m0 + wid * RA + lr) * 1024 + gcol;
  const unsigned short* gb = Bt + (size_t)(n0 + wid * 32 + lr) * 1024 + gcol;
  unsigned short* lA = &As[(wid * RA) * 64];
  unsigned short* lB = &Bs[(wid * 32) * 64];

  f32x4 acc[NI][4];
#pragma unroll
  for (int i = 0; i < NI; i++)
#pragma unroll
    for (int j = 0; j < 4; j++) acc[i][j] = (f32x4){0.f, 0.f, 0.f, 0.f};

  bool sw = (MODE == 1) || (wsel != 2);         // swapped-operand (wave-uniform)

  for (int k0 = 0; k0 < 1024; k0 += 64) {
#pragma unroll
    for (int i = 0; i < RA / 8; i++) async16(ga + i * 8 * 1024 + k0, lA + i * 8 * 64);
#pragma unroll
    for (int j = 0; j < 4; j++)      async16(gb + j * 8 * 1024 + k0, lB + j * 8 * 64);
    __syncthreads();                             // staging visible (vmcnt drained)
#pragma unroll
    for (int ks = 0; ks < 2; ks++) {
      s16x8 af[NI], bf[4];
#pragma unroll
      for (int i = 0; i < NI; i++)
        af[i] = *(const s16x8*)&As[(wm + i * 16 + c) * 64 + (((ks * 4 + quad) ^ (c & 7)) << 3)];
#pragma unroll
      for (int j = 0; j < 4; j++)
        bf[j] = *(const s16x8*)&Bs[(wn + j * 16 + c) * 64 + (((ks * 4 + quad) ^ (c & 7)) << 3)];
      if (sw) {
#pragma unroll
        for (int i = 0; i < NI; i++)
#pragma unroll
          for (int j = 0; j < 4; j++)
            acc[i][j] = __builtin_amdgcn_mfma_f32_16x16x32_bf16(bf[j], af[i], acc[i][j], 0, 0, 0);
      } else {
#pragma unroll
        for (int i = 0; i < NI; i++)
#pragma unroll
          for (int j = 0; j < 4; j++)
            acc[i][j] = __builtin_amdgcn_mfma_f32_16x16x32_bf16(af[i], bf[j], acc[i][j], 0, 0, 0);
      }
    }
    __syncthreads();                             // all reads done before re-stage
  }

  if (MODE == 1) {
    // swapped: row=feature (4-contig), col=token -> float4 stores
#pragma unroll
    for (int j = 0; j < 4; j++) {
      int colb = n0 + wn + j * 16 + quad * 4;
      f32x4 bvv = *(const f32x4*)&bias[colb];
#pragma unroll
      for (int i = 0; i < NI; i++) {
        int s_tok = m0 + wm + i * 16 + c;
        f32x4 v = acc[i][j] + bvv;
        *(f32x4*)&outF[(size_t)s_tok * 1024 + colb] = v;
      }
    }
  } else if (wsel == 2) {
#pragma unroll
    for (int j = 0; j < 4; j++) {
      int col = n0 + wn + j * 16 + c;
      float bv = bias[col];
      int h = col >> 6, d = col & 63;
#pragma unroll
      for (int i = 0; i < NI; i++) {
        int row = m0 + wm + i * 16 + quad * 4;
        int bb = row >> 10, s = row & 1023;
        u16x4 pk;
#pragma unroll
        for (int r = 0; r < 4; r++) pk[r] = f2bf(acc[i][j][r] + bv);
        *(u16x4*)&outV[(size_t)(((bb * 16 + h) * 64 + d)) * 1024 + s] = pk;
      }
    }
  } else {
    float sc = (wsel == 0) ? QSCALE : 1.0f;
#pragma unroll
    for (int j = 0; j < 4; j++) {
      int colb = n0 + wn + j * 16 + quad * 4;
      f32x4 bvv = *(const f32x4*)&bias[colb];
      int h = colb >> 6, d0 = colb & 63;
#pragma unroll
      for (int i = 0; i < NI; i++) {
        int s_tok = m0 + wm + i * 16 + c;
        int bb = s_tok >> 10, s = s_tok & 1023;
        u16x4 pk;
#pragma unroll
        for (int r = 0; r < 4; r++) pk[r] = f2bf((acc[i][j][r] + bvv[r]) * sc);
        *(u16x4*)&outB[(size_t)wsel * 4194304 + (((bb * 16 + h) * 1024 + s) * 64) + d0] = pk;
      }
    }
  }
}

// ---------------- QKV GEMM: 256x256 tile, 8 waves, phase-split + vmcnt(N) ---
// One quadrant: 16 mfma over acc[MB..MB+3][NB..NB+1], frags AFR[4][2], BFR[2][2].
#define QKV_QUAD(AFR, BFR, MB, NB)                                            \
  if (sw) {                                                                   \
    _Pragma("unroll") for (int ks = 0; ks < 2; ks++)                          \
    _Pragma("unroll") for (int mf = 0; mf < 4; mf++)                          \
    _Pragma("unroll") for (int nf = 0; nf < 2; nf++)                          \
      acc[(MB) + mf][(NB) + nf] = __builtin_amdgcn_mfma_f32_16x16x32_bf16(    \
          BFR[nf][ks], AFR[mf][ks], acc[(MB) + mf][(NB) + nf], 0, 0, 0);      \
  } else {                                                                    \
    _Pragma("unroll") for (int ks = 0; ks < 2; ks++)                          \
    _Pragma("unroll") for (int mf = 0; mf < 4; mf++)                          \
    _Pragma("unroll") for (int nf = 0; nf < 2; nf++)                          \
      acc[(MB) + mf][(NB) + nf] = __builtin_amdgcn_mfma_f32_16x16x32_bf16(    \
          AFR[mf][ks], BFR[nf][ks], acc[(MB) + mf][(NB) + nf], 0, 0, 0);      \
  }

// One BK=64 K-tile on buffer (Ac,Bc). Quadrant order minimizes live frags:
//  P0: read a0(8)+b01(4) | bar | lgkm0 | Q(a0,b01)->acc[0..3][0..1] | bar
//  P1: read a1(8)        | bar | lgkm0 | Q(a1,b01)->acc[4..7][0..1] | bar
//      (all A-reads drained at P1's lgkm0 -> A restage safe in P2)
//  P2: read b23(4) + stage A(4) | bar | lgkm0 | Q(a1,b23)->acc[4..7][2..3] | bar
//      (all B-reads drained at P2's lgkm0 -> B restage safe in P3)
//  P3: stage B(4) | bar | Q(a0,b23)->acc[0..3][2..3] | vmcnt(8) | bar
// Live frags peak ~80 regs (a0 32 + a1 32 + one b-half 16).
template <bool STAGE, int VMN>
__device__ __forceinline__ void qkv_ktile(
    unsigned short* Ac, unsigned short* Bc,
    const unsigned short* ga, const unsigned short* gb, int k2,
    int wid, int wm, int wn, int c, int quad, bool sw, f32x4 (&acc)[8][4]) {
  const int cs = c & 7;
  s16x8 a0[4][2], a1[4][2], bf[2][2];
  // ---- P0
#pragma unroll
  for (int mf = 0; mf < 4; mf++)
#pragma unroll
    for (int ks = 0; ks < 2; ks++)
      a0[mf][ks] = *(const s16x8*)&Ac[(wm * 128 + mf * 16 + c) * 64 + (((ks * 4 + quad) ^ cs) << 3)];
#pragma unroll
  for (int nf = 0; nf < 2; nf++)
#pragma unroll
    for (int ks = 0; ks < 2; ks++)
      bf[nf][ks] = *(const s16x8*)&Bc[(wn * 64 + nf * 16 + c) * 64 + (((ks * 4 + quad) ^ cs) << 3)];
  __builtin_amdgcn_s_barrier();
  __asm__ volatile("s_waitcnt lgkmcnt(0)" ::: "memory");
  __builtin_amdgcn_s_setprio(1);
  QKV_QUAD(a0, bf, 0, 0)
  __builtin_amdgcn_s_setprio(0);
  __builtin_amdgcn_s_barrier();
  // ---- P1
#pragma unroll
  for (int mf = 0; mf < 4; mf++)
#pragma unroll
    for (int ks = 0; ks < 2; ks++)
      a1[mf][ks] = *(const s16x8*)&Ac[(wm * 128 + 64 + mf * 16 + c) * 64 + (((ks * 4 + quad) ^ cs) << 3)];
  __builtin_amdgcn_s_barrier();
  __asm__ volatile("s_waitcnt lgkmcnt(0)" ::: "memory");   // all A-reads drained
  __builtin_amdgcn_s_setprio(1);
  QKV_QUAD(a1, bf, 4, 0)
  __builtin_amdgcn_s_setprio(0);
  __builtin_amdgcn_s_barrier();                            // licenses A restage
  // ---- P2
#pragma unroll
  for (int nf = 0; nf < 2; nf++)
#pragma unroll
    for (int ks = 0; ks < 2; ks++)
      bf[nf][ks] = *(const s16x8*)&Bc[(wn * 64 + (2 + nf) * 16 + c) * 64 + (((ks * 4 + quad) ^ cs) << 3)];
  if constexpr (STAGE) {
#pragma unroll
    for (int j = 0; j < 4; j++)
      async16(ga + j * 8 * 1024 + k2, Ac + (wid * 32 + j * 8) * 64);
  }
  __builtin_amdgcn_s_barrier();
  __asm__ volatile("s_waitcnt lgkmcnt(0)" ::: "memory");   // all B-reads drained
  __builtin_amdgcn_s_setprio(1);
  QKV_QUAD(a1, bf, 4, 2)
  __builtin_amdgcn_s_setprio(0);
  __builtin_amdgcn_s_barrier();                            // licenses B restage
  // ---- P3
  if constexpr (STAGE) {
#pragma unroll
    for (int j = 0; j < 4; j++)
      async16(gb + j * 8 * 1024 + k2, Bc + (wid * 32 + j * 8) * 64);
  }
  __builtin_amdgcn_s_barrier();
  __builtin_amdgcn_s_setprio(1);
  QKV_QUAD(a0, bf, 0, 2)
  __builtin_amdgcn_s_setprio(0);
  if constexpr (VMN == 8)
    __asm__ volatile("s_waitcnt vmcnt(8)" ::: "memory");
  else if constexpr (VMN == 0)
    __asm__ volatile("s_waitcnt vmcnt(0)" ::: "memory");
  __builtin_amdgcn_s_barrier();
}

// grid (12,16): x = wsel*4 + n-tile, y = m-tile. 512 threads = 8 waves 2Mx4N;
// per-wave output 128x64. LDS 128KB = dbuf (A 256x64 + B 256x64) bf16,
// reused post-loop as 8 x 16KB per-wave transpose buffers for the epilogue.
__global__ __launch_bounds__(512, 1) void k_qkv256(
    const unsigned short* __restrict__ A,
    const unsigned short* __restrict__ WtBase,
    const float* __restrict__ bq, const float* __restrict__ bk,
    const float* __restrict__ bv,
    unsigned short* __restrict__ outQK, unsigned short* __restrict__ outV) {
  __shared__ unsigned short SMEM[65536];        // 128 KB flat
  unsigned short* As0 = SMEM;
  unsigned short* As1 = SMEM + 16384;
  unsigned short* Bs0 = SMEM + 32768;
  unsigned short* Bs1 = SMEM + 49152;
  int tid = threadIdx.x, wid = tid >> 6, lane = tid & 63;
  int c = lane & 15, quad = lane >> 4;
  int wm = wid >> 2, wn = wid & 3;
  int wsel = blockIdx.x >> 2;
  int n0 = (blockIdx.x & 3) * 256;
  int m0 = blockIdx.y * 256;
  const unsigned short* Bt = WtBase + (size_t)wsel * 1048576;
  const float* bias = (wsel == 0) ? bq : ((wsel == 1) ? bk : bv);
  bool sw = (wsel != 2);                         // Q/K swapped-operand

  int lr = lane >> 3, lc = lane & 7;
  int gcol = (lc ^ lr) << 3;                     // XOR-swizzled source chunk
  const unsigned short* ga = A  + (size_t)(m0 + wid * 32 + lr) * 1024 + gcol;
  const unsigned short* gb = Bt + (size_t)(n0 + wid * 32 + lr) * 1024 + gcol;

  f32x4 acc[8][4];
#pragma unroll
  for (int i = 0; i < 8; i++)
#pragma unroll
    for (int j = 0; j < 4; j++) acc[i][j] = (f32x4){0.f, 0.f, 0.f, 0.f};

  // prologue: K-tile 0 -> buf0 (8 loads), K-tile 1 -> buf1 (8 loads)
#pragma unroll
  for (int j = 0; j < 4; j++) {
    async16(ga + j * 8 * 1024,      As0 + (wid * 32 + j * 8) * 64);
    async16(gb + j * 8 * 1024,      Bs0 + (wid * 32 + j * 8) * 64);
  }
#pragma unroll
  for (int j = 0; j < 4; j++) {
    async16(ga + j * 8 * 1024 + 64, As1 + (wid * 32 + j * 8) * 64);
    async16(gb + j * 8 * 1024 + 64, Bs1 + (wid * 32 + j * 8) * 64);
  }
  __asm__ volatile("s_waitcnt vmcnt(8)" ::: "memory");   // K-tile 0 landed
  __builtin_amdgcn_s_barrier();

  for (int kt = 0; kt < 14; kt += 2) {
    qkv_ktile<true, 8>(As0, Bs0, ga, gb, (kt + 2) * 64,
                       wid, wm, wn, c, quad, sw, acc);
    qkv_ktile<true, 8>(As1, Bs1, ga, gb, (kt + 3) * 64,
                       wid, wm, wn, c, quad, sw, acc);
  }
  qkv_ktile<false, 0>(As0, Bs0, ga, gb, 0, wid, wm, wn, c, quad, sw, acc);
  qkv_ktile<false, -1>(As1, Bs1, ga, gb, 0, wid, wm, wn, c, quad, sw, acc);
  // final s_barrier done inside; all K-loop LDS reads drained -> LDS reusable.

  // ---- epilogue: per-wave LDS transpose -> full-line coalesced stores ----
  unsigned short* W = SMEM + wid * 8192;         // private 16KB per wave
  int tokbase = m0 + wm * 128;
  int bb = tokbase >> 10, s0 = tokbase & 1023;   // 128-aligned, single b
  int h = (n0 + wn * 64) >> 6;

  if (!sw) {
    // V: value(tok = mf*16+quad*4+r, d = nf*16+c). LDS [d][128 tok] bf16,
    // 256B rows = 16 chunks of 16B, chunk-swizzled by (d&15).
#pragma unroll
    for (int nf = 0; nf < 4; nf++) {
      int col = n0 + wn * 64 + nf * 16 + c;
      float bvv = bias[col];
      int d = nf * 16 + c;                       // local d, 0..63
#pragma unroll
      for (int mf = 0; mf < 8; mf++) {
        u16x4 pk;
#pragma unroll
        for (int r = 0; r < 4; r++) pk[r] = f2bf(acc[mf][nf][r] + bvv);
        int ch = mf * 2 + (quad >> 1);           // 16B chunk 0..15
        int chs = ch ^ c;                        // swizzle by (d&15)==c
        *(u16x4*)&W[d * 128 + chs * 8 + (quad & 1) * 4] = pk;
      }
    }
    __asm__ volatile("s_waitcnt lgkmcnt(0)" ::: "memory");
    int r16 = lane >> 4, chl = lane & 15;
    unsigned short* gw = outV + ((size_t)(bb * 16 + h) * 64) * 1024 + s0;
#pragma unroll
    for (int t = 0; t < 16; t++) {
      int d = t * 4 + r16;
      int chs = chl ^ (d & 15);
      u16x8 vv = *(const u16x8*)&W[d * 128 + chs * 8];
      *(u16x8*)&gw[(size_t)d * 1024 + chl * 8] = vv;  // 4x256B segments/instr
    }
  } else {
    // Q/K: value(tok = mf*16+c, d = nf*16+quad*4+r). LDS [tok][64 d] bf16,
    // 128B rows = 8 chunks of 16B, chunk-swizzled by (tok&7).
    float sc = (wsel == 0) ? QSCALE : 1.0f;
#pragma unroll
    for (int nf = 0; nf < 4; nf++) {
      int colb = n0 + wn * 64 + nf * 16 + quad * 4;
      f32x4 bvv = *(const f32x4*)&bias[colb];
#pragma unroll
      for (int mf = 0; mf < 8; mf++) {
        u16x4 pk;
#pragma unroll
        for (int r = 0; r < 4; r++) pk[r] = f2bf((acc[mf][nf][r] + bvv[r]) * sc);
        int tok = mf * 16 + c;                   // local token, 0..127
        int ch = nf * 2 + (quad >> 1);           // 16B chunk 0..7
        int chs = ch ^ (tok & 7);
        *(u16x4*)&W[tok * 64 + chs * 8 + (quad & 1) * 4] = pk;
      }
    }
    __asm__ volatile("s_waitcnt lgkmcnt(0)" ::: "memory");
    int r8 = lane >> 3, chl = lane & 7;
    unsigned short* outp = outQK + (size_t)wsel * 4194304;
    unsigned short* gw = outp + ((size_t)(bb * 16 + h) * 1024 + s0) * 64;
#pragma unroll
    for (int t = 0; t < 16; t++) {
      int tok = t * 8 + r8;
      int chs = chl ^ (tok & 7);
      u16x8 vv = *(const u16x8*)&W[tok * 64 + chs * 8];
      *(u16x8*)&gw[tok * 64 + chl * 8] = vv;     // 1KB contiguous/instr
    }
  }
}

// ---------------- Flash attention, 16x16x32 MFMA, streaming softmax ---------
__global__ __launch_bounds__(256) void k_attn(
    const unsigned short* __restrict__ Q, const unsigned short* __restrict__ K,
    const unsigned short* __restrict__ Vt, const float* __restrict__ colbias,
    const int* __restrict__ nearest, unsigned short* __restrict__ AO) {
  __shared__ unsigned short Ks[64 * 72];     // [key][d]
  __shared__ unsigned short Vs[64 * 72];     // [d][key]
  __shared__ unsigned short Ps[4][32 * 72];  // per-wave [q][key]
  __shared__ float Cb[1024];
  int tid = threadIdx.x, wid = tid >> 6, lane = tid & 63;
  int c = lane & 15, quad = lane >> 4;
  int bh = blockIdx.x, qt = blockIdx.y;
  int b = bh >> 4, head = bh & 15;
  int q0 = qt * 128, wq = wid * 32;
  const unsigned short* Qg = Q  + (size_t)(bh * 1024 + q0 + wq) * 64;
  const unsigned short* Kg = K  + (size_t)bh * 1024 * 64;
  const unsigned short* Vg = Vt + (size_t)bh * 64 * 1024;

  *(float4*)&Cb[tid * 4] = *(const float4*)&colbias[b * 1024 + tid * 4];

  s16x8 qf[2][2];
#pragma unroll
  for (int nt = 0; nt < 2; nt++)
#pragma unroll
    for (int ks = 0; ks < 2; ks++)
      qf[nt][ks] = *(const s16x8*)&Qg[(nt * 16 + c) * 64 + ks * 32 + quad * 8];

  int nq[2];
  nq[0] = nearest[b * 1024 + q0 + wq + c];
  nq[1] = nearest[b * 1024 + q0 + wq + 16 + c];

  f32x4 o[2][4];
#pragma unroll
  for (int i = 0; i < 2; i++)
#pragma unroll
    for (int j = 0; j < 4; j++) o[i][j] = (f32x4){0.f, 0.f, 0.f, 0.f};
  float lrun[2] = {0.f, 0.f};

  int srow = tid >> 3, scol8 = (tid & 7) * 8;

  u16x8 kr[2], vr[2];
#pragma unroll
  for (int it = 0; it < 2; ++it) {
    int r2 = it * 32 + srow;
    kr[it] = *(const u16x8*)&Kg[r2 * 64 + scol8];
    vr[it] = *(const u16x8*)&Vg[r2 * 1024 + scol8];
  }
  __syncthreads();   // Cb visible before first use

  for (int kc = 0; kc < 16; ++kc) {
#pragma unroll
    for (int it = 0; it < 2; ++it) {
      int r2 = it * 32 + srow;
      *(u16x8*)&Ks[r2 * 72 + scol8] = kr[it];
      *(u16x8*)&Vs[r2 * 72 + scol8] = vr[it];
    }
    __syncthreads();
    if (kc < 15) {
#pragma unroll
      for (int it = 0; it < 2; ++it) {
        int r2 = it * 32 + srow;
        kr[it] = *(const u16x8*)&Kg[((kc + 1) * 64 + r2) * 64 + scol8];
        vr[it] = *(const u16x8*)&Vg[r2 * 1024 + (kc + 1) * 64 + scol8];
      }
    }

    // S^T = K . Q^T : st[mt][nt] (key = mt*16+quad*4+r, q = nt*16+c)
    f32x4 st[4][2];
#pragma unroll
    for (int mt = 0; mt < 4; mt++)
#pragma unroll
      for (int nt = 0; nt < 2; nt++) st[mt][nt] = (f32x4){0.f, 0.f, 0.f, 0.f};
#pragma unroll
    for (int mt = 0; mt < 4; mt++)
#pragma unroll
      for (int ks = 0; ks < 2; ks++) {
        s16x8 a = *(const s16x8*)&Ks[(mt * 16 + c) * 72 + ks * 32 + quad * 8];
#pragma unroll
        for (int nt = 0; nt < 2; nt++)
          st[mt][nt] = __builtin_amdgcn_mfma_f32_16x16x32_bf16(a, qf[nt][ks], st[mt][nt], 0, 0, 0);
      }

    // rare verb-bias fixup: nq lands in this chunk for at most one element
    bool h0 = (nq[0] >> 6) == kc;
    bool h1 = (nq[1] >> 6) == kc;
    if (__any(h0 || h1)) {
#pragma unroll
      for (int mt = 0; mt < 4; mt++)
#pragma unroll
        for (int nt = 0; nt < 2; nt++)
#pragma unroll
          for (int r = 0; r < 4; r++)
            if (kc * 64 + mt * 16 + quad * 4 + r == nq[nt]) st[mt][nt][r] += VERB2;
    }

    // hot path: cb add + exp2 + v_perm truncate-pack; l from packed values
#pragma unroll
    for (int mt = 0; mt < 4; mt++) {
      f32x4 cb = *(const f32x4*)&Cb[kc * 64 + mt * 16 + quad * 4];
#pragma unroll
      for (int nt = 0; nt < 2; nt++) {
        float e0 = EXP2F(st[mt][nt][0] + cb[0]);
        float e1 = EXP2F(st[mt][nt][1] + cb[1]);
        float e2 = EXP2F(st[mt][nt][2] + cb[2]);
        float e3 = EXP2F(st[mt][nt][3] + cb[3]);
        unsigned p01 = __builtin_amdgcn_perm(__float_as_uint(e1), __float_as_uint(e0), 0x07060302u);
        unsigned p23 = __builtin_amdgcn_perm(__float_as_uint(e3), __float_as_uint(e2), 0x07060302u);
        lrun[nt] += __uint_as_float(p01 << 16) + __uint_as_float(p01 & 0xffff0000u)
                  + __uint_as_float(p23 << 16) + __uint_as_float(p23 & 0xffff0000u);
        uint2 pk; pk.x = p01; pk.y = p23;
        *(uint2*)&Ps[wid][(nt * 16 + c) * 72 + mt * 16 + quad * 4] = pk;
      }
    }
    __asm__ volatile("s_waitcnt lgkmcnt(0)" ::: "memory");

    // O += (P . V) computed SWAPPED: o[mtq][ntd] rows = d, cols = q
#pragma unroll
    for (int ks = 0; ks < 2; ks++) {
      s16x8 pa[2];
#pragma unroll
      for (int mtq = 0; mtq < 2; mtq++)
        pa[mtq] = *(const s16x8*)&Ps[wid][(mtq * 16 + c) * 72 + ks * 32 + quad * 8];
#pragma unroll
      for (int ntd = 0; ntd < 4; ntd++) {
        s16x8 vb = *(const s16x8*)&Vs[(ntd * 16 + c) * 72 + ks * 32 + quad * 8];
#pragma unroll
        for (int mtq = 0; mtq < 2; mtq++)
          o[mtq][ntd] = __builtin_amdgcn_mfma_f32_16x16x32_bf16(vb, pa[mtq], o[mtq][ntd], 0, 0, 0);
      }
    }
    __syncthreads();
  }

  // l-reduction across quads; lane's own token = mtq*16+c -> no shuffle
#pragma unroll
  for (int nt = 0; nt < 2; nt++) {
    lrun[nt] += __shfl_xor(lrun[nt], 16, 64);
    lrun[nt] += __shfl_xor(lrun[nt], 32, 64);
  }
  float linv[2] = {1.0f / lrun[0], 1.0f / lrun[1]};
#pragma unroll
  for (int mtq = 0; mtq < 2; mtq++) {
    size_t row = (size_t)(b * 1024 + q0 + wq + mtq * 16 + c);
#pragma unroll
    for (int ntd = 0; ntd < 4; ntd++) {
      int d0 = ntd * 16 + quad * 4;
      u16x4 pk;
#pragma unroll
      for (int r = 0; r < 4; r++) pk[r] = f2bf(o[mtq][ntd][r] * linv[mtq]);
      *(u16x4*)&AO[row * 1024 + head * 64 + d0] = pk;
    }
  }
}

// ---------------------------------------------------------------------------
extern "C" void kernel_launch(void* const* d_in, const int* in_sizes, int n_in,
                              void* d_out, int out_size, void* d_ws, size_t ws_size,
                              hipStream_t stream) {
  const float* hs     = (const float*)d_in[0];
  const int*   morpho = (const int*)d_in[1];
  const float* Wq = (const float*)d_in[2];
  const float* bq = (const float*)d_in[3];
  const float* Wk = (const float*)d_in[4];
  const float* bk = (const float*)d_in[5];
  const float* Wv = (const float*)d_in[6];
  const float* bv = (const float*)d_in[7];
  const float* Wo = (const float*)d_in[8];
  const float* bo = (const float*)d_in[9];
  float* out = (float*)d_out;

  char* ws = (char*)d_ws;
  unsigned short* hsb = (unsigned short*)(ws);                    // 8 MB [4096][1024]
  unsigned short* Wt  = (unsigned short*)(ws + (8u << 20));       // 8 MB [4][1024][1024]
  unsigned short* Qb  = (unsigned short*)(ws + (16u << 20));      // Q +16MB, K +24MB
  unsigned short* Kb  = (unsigned short*)(ws + (24u << 20));
  unsigned short* Vtb = (unsigned short*)(ws + (40u << 20));      // 8 MB [B,NH,HD,S]
  float* colbias      = (float*)(ws + (48u << 20));               // 16 KB
  int*   nearestp     = (int*)(ws + (48u << 20) + (16u << 10));   // 16 KB
  unsigned short* AO  = hsb;  // reuse: hs_bf16 dead after QKV GEMM

  k_prep<<<3088, 256, 0, stream>>>(hs, hsb, Wq, Wk, Wv, Wo, Wt, morpho,
                                   colbias, nearestp);
  k_qkv256<<<dim3(12, 16), 512, 0, stream>>>(hsb, Wt, bq, bk, bv, Qb, Vtb);
  k_attn<<<dim3(64, 8), 256, 0, stream>>>(Qb, Kb, Vtb, colbias, nearestp, AO);
  k_gemm<1><<<dim3(8, 64), 256, 0, stream>>>(AO, Wt + 3 * 1048576, bo, nullptr, nullptr,
                                             nullptr, nullptr, out);
  (void)in_sizes; (void)n_in; (void)out_size; (void)ws_size; (void)Kb;
}

// Round 4
// 210.248 us; speedup vs baseline: 1.3590x; 1.3448x over previous
//
#include <hip/hip_runtime.h>

// ---------------------------------------------------------------------------
// AgglutinativeAttention: hs->QKV proj -> morpho-biased softmax attn -> out proj
// B=4 S=1024 H=1024 NH=16 HD=64.  bf16 MFMA throughout.
// R12: QKV geometry fixed to fit the register file. A 512-thread block is
//      8 waves = 2 waves/SIMD minimum -> hard cap 256 regs/wave (unified
//      VGPR+AGPR), unreachable by launch_bounds. The 256x256 tile (acc 128 +
//      frags 80+) could never fit -> compiler spilled ~190MB/dispatch to
//      scratch (R9-R11's WRITE_SIZE, first-dispatch first-touch anomaly).
//      Now: 256x128 tile, 8 waves 4Mx2N, 64x64/wave -> acc[4][4]=64 AGPR +
//      64 frag VGPR + ~30 addr = ~160 regs, no spill. Same 4-phase counted
//      vmcnt(6) protocol, same XOR swizzle, R10's full-line LDS-transpose
//      epilogue resized to 64x64/wave. Grid (24,16)=384 blocks, LDS 96KB.
// ---------------------------------------------------------------------------

#define QSCALE 0.18033688011112042f   /* 0.125 * log2(e) */
#define CB0    1.0820212806667225f    /* 0.75 * log2(e) */
#define CB1    0.5193702147200268f    /* 0.36 * log2(e) */
#define VERB2  2.8853900817779268f    /* 2.0  * log2(e) */

typedef float  f32x4   __attribute__((ext_vector_type(4)));
typedef short  s16x8   __attribute__((ext_vector_type(8)));
typedef unsigned short u16x4 __attribute__((ext_vector_type(4)));
typedef unsigned short u16x8 __attribute__((ext_vector_type(8)));

#if __has_builtin(__builtin_amdgcn_exp2f)
#define EXP2F(x) __builtin_amdgcn_exp2f(x)
#else
#define EXP2F(x) exp2f(x)
#endif

__device__ __forceinline__ unsigned short f2bf(float f) {
  union { float f; unsigned u; } a; a.f = f;
  unsigned r = a.u + 0x7fffu + ((a.u >> 16) & 1u);   // RNE
  return (unsigned short)(r >> 16);
}

__device__ __forceinline__ void async16(const void* g, void* l) {
  __builtin_amdgcn_global_load_lds(
      (const __attribute__((address_space(1))) unsigned int*)g,
      (__attribute__((address_space(3))) unsigned int*)l, 16, 0, 0);
}

// ---------------- fused prep: cvt (2048) | weight-T x4 (1024) | bias (16) ---
__global__ __launch_bounds__(256) void k_prep(
    const float* __restrict__ hs, unsigned short* __restrict__ hsb,
    const float* __restrict__ Wq, const float* __restrict__ Wk,
    const float* __restrict__ Wv, const float* __restrict__ Wo,
    unsigned short* __restrict__ Wt, const int* __restrict__ mt,
    float* __restrict__ colbias, int* __restrict__ nearest) {
  __shared__ float t[64 * 68];
  int bx = blockIdx.x, tid = threadIdx.x;
  if (bx < 2048) {
    int i = (bx * 256 + tid) * 8;
    float4 v0 = *(const float4*)(hs + i);
    float4 v1 = *(const float4*)(hs + i + 4);
    u16x8 o;
    o[0] = f2bf(v0.x); o[1] = f2bf(v0.y); o[2] = f2bf(v0.z); o[3] = f2bf(v0.w);
    o[4] = f2bf(v1.x); o[5] = f2bf(v1.y); o[6] = f2bf(v1.z); o[7] = f2bf(v1.w);
    *(u16x8*)(hsb + i) = o;
  } else if (bx < 3072) {
    int w = (bx - 2048) >> 8, tt = (bx - 2048) & 255;
    const float* W = (w == 0) ? Wq : (w == 1) ? Wk : (w == 2) ? Wv : Wo;
    unsigned short* Wd = Wt + (size_t)w * 1048576;
    int n0 = (tt & 15) * 64, k0 = (tt >> 4) * 64;
    int r = tid >> 2, c0 = (tid & 3) * 16;
    const float* src = &W[(k0 + r) * 1024 + n0 + c0];
    float4 a0 = *(const float4*)(src + 0);
    float4 a1 = *(const float4*)(src + 4);
    float4 a2 = *(const float4*)(src + 8);
    float4 a3 = *(const float4*)(src + 12);
    *(float4*)&t[r * 68 + c0 + 0]  = a0;
    *(float4*)&t[r * 68 + c0 + 4]  = a1;
    *(float4*)&t[r * 68 + c0 + 8]  = a2;
    *(float4*)&t[r * 68 + c0 + 12] = a3;
    __syncthreads();
    u16x8 o0, o1;
#pragma unroll
    for (int j = 0; j < 8; j++) {
      o0[j] = f2bf(t[(c0 + j) * 68 + r]);
      o1[j] = f2bf(t[(c0 + 8 + j) * 68 + r]);
    }
    *(u16x8*)&Wd[(n0 + r) * 1024 + k0 + c0]     = o0;
    *(u16x8*)&Wd[(n0 + r) * 1024 + k0 + c0 + 8] = o1;
  } else {
    int i = bx - 3072;
    int b = i >> 2;
    int* sm = (int*)t;
    for (int j = tid; j < 1024; j += 256) sm[j] = mt[b * 1024 + j];
    __syncthreads();
    int q = (i & 3) * 256 + tid;
    int best = 1 << 30, bj = -1;
    for (int j = 0; j < 1024; ++j) {
      int d = (q > j) ? (q - j) : (j - q);
      int dd = (sm[j] == 2) ? d : (1 << 30);
      if (dd < best) { best = dd; bj = j; }
    }
    nearest[b * 1024 + q] = bj;
    int m = sm[q];
    colbias[b * 1024 + q] = CB0 * (m == 0) + CB1 * (m == 1);
  }
}

// ---------------- out-proj GEMM (MODE 1 only), BK=64, XOR-swizzled ----------
template <int MODE>
__global__ __launch_bounds__(256) void k_gemm(
    const unsigned short* __restrict__ A,
    const unsigned short* __restrict__ WtBase,
    const float* __restrict__ bias0, const float* __restrict__ bias1,
    const float* __restrict__ bias2,
    unsigned short* __restrict__ outB, unsigned short* __restrict__ outV,
    float* __restrict__ outF) {
  constexpr int TM = (MODE == 0) ? 128 : 64;
  constexpr int NI = (MODE == 0) ? 4 : 2;       // m-fragments per wave
  constexpr int RA = TM / 4;                    // A rows staged per wave
  __shared__ unsigned short As[TM * 64];
  __shared__ unsigned short Bs[128 * 64];
  int tid = threadIdx.x, wid = tid >> 6, lane = tid & 63;
  int c = lane & 15, quad = lane >> 4;
  int m0, wsel, n0;
  const unsigned short* Bt;
  const float* bias;
  if (MODE == 0) {
    wsel = blockIdx.x >> 3;
    n0 = (blockIdx.x & 7) * 128;
    m0 = blockIdx.y * 128;
    Bt = WtBase + wsel * 1048576;
    bias = (wsel == 0) ? bias0 : ((wsel == 1) ? bias1 : bias2);
  } else {
    wsel = 0;
    n0 = blockIdx.x * 128;
    m0 = blockIdx.y * 64;
    Bt = WtBase; bias = bias0;
  }
  int wm = (wid >> 1) * (16 * NI), wn = (wid & 1) * 64;
  int lr = lane >> 3, lc = lane & 7;
  int gcol = ((lc ^ lr) << 3);                  // XOR-swizzled 16B chunk
  const unsigned short* ga = A  + (size_t)(m0 + wid * RA + lr) * 1024 + gcol;
  const unsigned short* gb = Bt + (size_t)(n0 + wid * 32 + lr) * 1024 + gcol;
  unsigned short* lA = &As[(wid * RA) * 64];
  unsigned short* lB = &Bs[(wid * 32) * 64];

  f32x4 acc[NI][4];
#pragma unroll
  for (int i = 0; i < NI; i++)
#pragma unroll
    for (int j = 0; j < 4; j++) acc[i][j] = (f32x4){0.f, 0.f, 0.f, 0.f};

  bool sw = (MODE == 1) || (wsel != 2);         // swapped-operand (wave-uniform)

  for (int k0 = 0; k0 < 1024; k0 += 64) {
#pragma unroll
    for (int i = 0; i < RA / 8; i++) async16(ga + i * 8 * 1024 + k0, lA + i * 8 * 64);
#pragma unroll
    for (int j = 0; j < 4; j++)      async16(gb + j * 8 * 1024 + k0, lB + j * 8 * 64);
    __syncthreads();                             // staging visible (vmcnt drained)
#pragma unroll
    for (int ks = 0; ks < 2; ks++) {
      s16x8 af[NI], bf[4];
#pragma unroll
      for (int i = 0; i < NI; i++)
        af[i] = *(const s16x8*)&As[(wm + i * 16 + c) * 64 + (((ks * 4 + quad) ^ (c & 7)) << 3)];
#pragma unroll
      for (int j = 0; j < 4; j++)
        bf[j] = *(const s16x8*)&Bs[(wn + j * 16 + c) * 64 + (((ks * 4 + quad) ^ (c & 7)) << 3)];
      if (sw) {
#pragma unroll
        for (int i = 0; i < NI; i++)
#pragma unroll
          for (int j = 0; j < 4; j++)
            acc[i][j] = __builtin_amdgcn_mfma_f32_16x16x32_bf16(bf[j], af[i], acc[i][j], 0, 0, 0);
      } else {
#pragma unroll
        for (int i = 0; i < NI; i++)
#pragma unroll
          for (int j = 0; j < 4; j++)
            acc[i][j] = __builtin_amdgcn_mfma_f32_16x16x32_bf16(af[i], bf[j], acc[i][j], 0, 0, 0);
      }
    }
    __syncthreads();                             // all reads done before re-stage
  }

  if (MODE == 1) {
    // swapped: row=feature (4-contig), col=token -> float4 stores
#pragma unroll
    for (int j = 0; j < 4; j++) {
      int colb = n0 + wn + j * 16 + quad * 4;
      f32x4 bvv = *(const f32x4*)&bias[colb];
#pragma unroll
      for (int i = 0; i < NI; i++) {
        int s_tok = m0 + wm + i * 16 + c;
        f32x4 v = acc[i][j] + bvv;
        *(f32x4*)&outF[(size_t)s_tok * 1024 + colb] = v;
      }
    }
  } else if (wsel == 2) {
#pragma unroll
    for (int j = 0; j < 4; j++) {
      int col = n0 + wn + j * 16 + c;
      float bv = bias[col];
      int h = col >> 6, d = col & 63;
#pragma unroll
      for (int i = 0; i < NI; i++) {
        int row = m0 + wm + i * 16 + quad * 4;
        int bb = row >> 10, s = row & 1023;
        u16x4 pk;
#pragma unroll
        for (int r = 0; r < 4; r++) pk[r] = f2bf(acc[i][j][r] + bv);
        *(u16x4*)&outV[(size_t)(((bb * 16 + h) * 64 + d)) * 1024 + s] = pk;
      }
    }
  } else {
    float sc = (wsel == 0) ? QSCALE : 1.0f;
#pragma unroll
    for (int j = 0; j < 4; j++) {
      int colb = n0 + wn + j * 16 + quad * 4;
      f32x4 bvv = *(const f32x4*)&bias[colb];
      int h = colb >> 6, d0 = colb & 63;
#pragma unroll
      for (int i = 0; i < NI; i++) {
        int s_tok = m0 + wm + i * 16 + c;
        int bb = s_tok >> 10, s = s_tok & 1023;
        u16x4 pk;
#pragma unroll
        for (int r = 0; r < 4; r++) pk[r] = f2bf((acc[i][j][r] + bvv[r]) * sc);
        *(u16x4*)&outB[(size_t)wsel * 4194304 + (((bb * 16 + h) * 1024 + s) * 64) + d0] = pk;
      }
    }
  }
}

// ---------------- QKV GEMM: 256x128 tile, 8 waves (64x64/wave), 4 phases ----
// One quadrant: 8 mfma over acc[MB..MB+1][NB..NB+1].
#define QKV_QUAD(MB, NB)                                                      \
  if (sw) {                                                                   \
    _Pragma("unroll") for (int ks = 0; ks < 2; ks++)                          \
    _Pragma("unroll") for (int mf = 0; mf < 2; mf++)                          \
    _Pragma("unroll") for (int nf = 0; nf < 2; nf++)                          \
      acc[(MB) + mf][(NB) + nf] = __builtin_amdgcn_mfma_f32_16x16x32_bf16(    \
          bfr[(NB) + nf][ks], afr[(MB) + mf][ks], acc[(MB) + mf][(NB) + nf], 0, 0, 0); \
  } else {                                                                    \
    _Pragma("unroll") for (int ks = 0; ks < 2; ks++)                          \
    _Pragma("unroll") for (int mf = 0; mf < 2; mf++)                          \
    _Pragma("unroll") for (int nf = 0; nf < 2; nf++)                          \
      acc[(MB) + mf][(NB) + nf] = __builtin_amdgcn_mfma_f32_16x16x32_bf16(    \
          afr[(MB) + mf][ks], bfr[(NB) + nf][ks], acc[(MB) + mf][(NB) + nf], 0, 0, 0); \
  }

// One BK=64 K-tile on buffer (Ac 256x64, Bc 128x64):
//  P0: read a01(4 ds) + b01(4) | bar | lgkm0 | quad(0,0) | bar
//  P1: read a23(4) + b23(4)    | bar | lgkm0 | quad(2,2) | bar
//      (ALL reads of this buffer drained at P1's lgkm0 -> restage safe)
//  P2: stage A (4 gload_lds)   | bar | quad(0,2) | bar
//  P3: stage B (2 gload_lds)   | bar | quad(2,0) | vmcnt(6) | bar
// vmcnt(6): this tile's 6 loads (for kt+2) stay in flight; older landed.
template <bool STAGE, int VMN>
__device__ __forceinline__ void qkv_ktile(
    unsigned short* Ac, unsigned short* Bc,
    const unsigned short* ga, const unsigned short* gb, int k2,
    int wid, int wm, int wn, int c, int quad, bool sw, f32x4 (&acc)[4][4]) {
  const int cs = c & 7;
  s16x8 afr[4][2], bfr[4][2];
  // ---- P0
#pragma unroll
  for (int mf = 0; mf < 2; mf++)
#pragma unroll
    for (int ks = 0; ks < 2; ks++)
      afr[mf][ks] = *(const s16x8*)&Ac[(wm * 64 + mf * 16 + c) * 64 + (((ks * 4 + quad) ^ cs) << 3)];
#pragma unroll
  for (int nf = 0; nf < 2; nf++)
#pragma unroll
    for (int ks = 0; ks < 2; ks++)
      bfr[nf][ks] = *(const s16x8*)&Bc[(wn * 64 + nf * 16 + c) * 64 + (((ks * 4 + quad) ^ cs) << 3)];
  __builtin_amdgcn_s_barrier();
  __asm__ volatile("s_waitcnt lgkmcnt(0)" ::: "memory");
  __builtin_amdgcn_s_setprio(1);
  QKV_QUAD(0, 0)
  __builtin_amdgcn_s_setprio(0);
  __builtin_amdgcn_s_barrier();
  // ---- P1
#pragma unroll
  for (int mf = 2; mf < 4; mf++)
#pragma unroll
    for (int ks = 0; ks < 2; ks++)
      afr[mf][ks] = *(const s16x8*)&Ac[(wm * 64 + mf * 16 + c) * 64 + (((ks * 4 + quad) ^ cs) << 3)];
#pragma unroll
  for (int nf = 2; nf < 4; nf++)
#pragma unroll
    for (int ks = 0; ks < 2; ks++)
      bfr[nf][ks] = *(const s16x8*)&Bc[(wn * 64 + nf * 16 + c) * 64 + (((ks * 4 + quad) ^ cs) << 3)];
  __builtin_amdgcn_s_barrier();
  __asm__ volatile("s_waitcnt lgkmcnt(0)" ::: "memory");   // ALL reads drained
  __builtin_amdgcn_s_setprio(1);
  QKV_QUAD(2, 2)
  __builtin_amdgcn_s_setprio(0);
  __builtin_amdgcn_s_barrier();                            // licenses restage
  // ---- P2
  if constexpr (STAGE) {
#pragma unroll
    for (int j = 0; j < 4; j++)
      async16(ga + j * 8 * 1024 + k2, Ac + (wid * 32 + j * 8) * 64);
  }
  __builtin_amdgcn_s_barrier();
  __builtin_amdgcn_s_setprio(1);
  QKV_QUAD(0, 2)
  __builtin_amdgcn_s_setprio(0);
  __builtin_amdgcn_s_barrier();
  // ---- P3
  if constexpr (STAGE) {
#pragma unroll
    for (int j = 0; j < 2; j++)
      async16(gb + j * 8 * 1024 + k2, Bc + (wid * 16 + j * 8) * 64);
  }
  __builtin_amdgcn_s_barrier();
  __builtin_amdgcn_s_setprio(1);
  QKV_QUAD(2, 0)
  __builtin_amdgcn_s_setprio(0);
  if constexpr (VMN == 6)
    __asm__ volatile("s_waitcnt vmcnt(6)" ::: "memory");
  else if constexpr (VMN == 0)
    __asm__ volatile("s_waitcnt vmcnt(0)" ::: "memory");
  __builtin_amdgcn_s_barrier();
}

// grid (24,16): x = wsel*8 + n-tile (128 cols), y = m-tile (256 tokens).
// 512 threads = 8 waves as 4(M)x2(N); per-wave output 64x64.
// LDS 96KB = dbuf (A 256x64 32KB + B 128x64 16KB); reused post-loop as
// 8 x 8KB per-wave transpose buffers for the full-line store epilogue.
__global__ __launch_bounds__(512, 2) void k_qkv(
    const unsigned short* __restrict__ A,
    const unsigned short* __restrict__ WtBase,
    const float* __restrict__ bq, const float* __restrict__ bk,
    const float* __restrict__ bv,
    unsigned short* __restrict__ outQK, unsigned short* __restrict__ outV) {
  __shared__ unsigned short SMEM[49152];        // 96 KB flat
  unsigned short* As0 = SMEM;                   // 256x64
  unsigned short* As1 = SMEM + 16384;
  unsigned short* Bs0 = SMEM + 32768;           // 128x64
  unsigned short* Bs1 = SMEM + 40960;
  int tid = threadIdx.x, wid = tid >> 6, lane = tid & 63;
  int c = lane & 15, quad = lane >> 4;
  int wm = wid >> 1, wn = wid & 1;
  int wsel = blockIdx.x >> 3;
  int n0 = (blockIdx.x & 7) * 128;
  int m0 = blockIdx.y * 256;
  const unsigned short* Bt = WtBase + (size_t)wsel * 1048576;
  const float* bias = (wsel == 0) ? bq : ((wsel == 1) ? bk : bv);
  bool sw = (wsel != 2);                         // Q/K swapped-operand

  int lr = lane >> 3, lc = lane & 7;
  int gcol = (lc ^ lr) << 3;                     // XOR-swizzled source chunk
  const unsigned short* ga = A  + (size_t)(m0 + wid * 32 + lr) * 1024 + gcol;
  const unsigned short* gb = Bt + (size_t)(n0 + wid * 16 + lr) * 1024 + gcol;

  f32x4 acc[4][4];
#pragma unroll
  for (int i = 0; i < 4; i++)
#pragma unroll
    for (int j = 0; j < 4; j++) acc[i][j] = (f32x4){0.f, 0.f, 0.f, 0.f};

  // prologue: K-tile 0 -> buf0 (6 loads/thread), K-tile 1 -> buf1 (6)
#pragma unroll
  for (int j = 0; j < 4; j++) async16(ga + j * 8 * 1024,      As0 + (wid * 32 + j * 8) * 64);
#pragma unroll
  for (int j = 0; j < 2; j++) async16(gb + j * 8 * 1024,      Bs0 + (wid * 16 + j * 8) * 64);
#pragma unroll
  for (int j = 0; j < 4; j++) async16(ga + j * 8 * 1024 + 64, As1 + (wid * 32 + j * 8) * 64);
#pragma unroll
  for (int j = 0; j < 2; j++) async16(gb + j * 8 * 1024 + 64, Bs1 + (wid * 16 + j * 8) * 64);
  __asm__ volatile("s_waitcnt vmcnt(6)" ::: "memory");   // K-tile 0 landed
  __builtin_amdgcn_s_barrier();

  for (int kt = 0; kt < 14; kt += 2) {
    qkv_ktile<true, 6>(As0, Bs0, ga, gb, (kt + 2) * 64,
                       wid, wm, wn, c, quad, sw, acc);
    qkv_ktile<true, 6>(As1, Bs1, ga, gb, (kt + 3) * 64,
                       wid, wm, wn, c, quad, sw, acc);
  }
  qkv_ktile<false, 0>(As0, Bs0, ga, gb, 0, wid, wm, wn, c, quad, sw, acc);
  qkv_ktile<false, -1>(As1, Bs1, ga, gb, 0, wid, wm, wn, c, quad, sw, acc);
  // final s_barrier inside; all K-loop LDS reads drained -> LDS reusable.

  // ---- epilogue: per-wave 8KB LDS transpose -> full-line coalesced stores --
  unsigned short* W = SMEM + wid * 4096;         // private 8KB per wave
  int tokbase = m0 + wm * 64;
  int bb = tokbase >> 10, s0 = tokbase & 1023;   // 64-aligned, single batch
  int colg = n0 + wn * 64;                       // wave's 64-col slab
  int h = colg >> 6;
  int r8 = lane >> 3, chl = lane & 7;

  if (!sw) {
    // V (normal order): tok = mf*16+quad*4+r, d = nf*16+c.
    // LDS image [d][64 tok] bf16, 128B rows = 8 chunks, swizzled by (d&7).
#pragma unroll
    for (int nf = 0; nf < 4; nf++) {
      float bvv = bias[colg + nf * 16 + c];
      int d = nf * 16 + c;
#pragma unroll
      for (int mf = 0; mf < 4; mf++) {
        u16x4 pk;
#pragma unroll
        for (int r = 0; r < 4; r++) pk[r] = f2bf(acc[mf][nf][r] + bvv);
        int ch = mf * 2 + (quad >> 1);
        int chs = ch ^ (d & 7);
        *(u16x4*)&W[d * 64 + chs * 8 + (quad & 1) * 4] = pk;
      }
    }
    __asm__ volatile("s_waitcnt lgkmcnt(0)" ::: "memory");
    unsigned short* gw = outV + ((size_t)(bb * 16 + h) * 64) * 1024 + s0;
#pragma unroll
    for (int t = 0; t < 8; t++) {
      int d = t * 8 + r8;
      int chs = chl ^ (d & 7);
      u16x8 vv = *(const u16x8*)&W[d * 64 + chs * 8];
      *(u16x8*)&gw[(size_t)d * 1024 + chl * 8] = vv;  // 8x128B rows/instr
    }
  } else {
    // Q/K (swapped): tok = mf*16+c, d = nf*16+quad*4+r.
    // LDS image [tok][64 d] bf16, 128B rows = 8 chunks, swizzled by (tok&7).
    float sc = (wsel == 0) ? QSCALE : 1.0f;
#pragma unroll
    for (int nf = 0; nf < 4; nf++) {
      f32x4 bvv = *(const f32x4*)&bias[colg + nf * 16 + quad * 4];
#pragma unroll
      for (int mf = 0; mf < 4; mf++) {
        u16x4 pk;
#pragma unroll
        for (int r = 0; r < 4; r++) pk[r] = f2bf((acc[mf][nf][r] + bvv[r]) * sc);
        int tok = mf * 16 + c;
        int ch = nf * 2 + (quad >> 1);
        int chs = ch ^ (tok & 7);
        *(u16x4*)&W[tok * 64 + chs * 8 + (quad & 1) * 4] = pk;
      }
    }
    __asm__ volatile("s_waitcnt lgkmcnt(0)" ::: "memory");
    unsigned short* outp = outQK + (size_t)wsel * 4194304;
    unsigned short* gw = outp + ((size_t)(bb * 16 + h) * 1024 + s0) * 64;
#pragma unroll
    for (int t = 0; t < 8; t++) {
      int tok = t * 8 + r8;
      int chs = chl ^ (tok & 7);
      u16x8 vv = *(const u16x8*)&W[tok * 64 + chs * 8];
      *(u16x8*)&gw[tok * 64 + chl * 8] = vv;     // 1KB contiguous/instr
    }
  }
}

// ---------------- Flash attention, 16x16x32 MFMA, streaming softmax ---------
__global__ __launch_bounds__(256) void k_attn(
    const unsigned short* __restrict__ Q, const unsigned short* __restrict__ K,
    const unsigned short* __restrict__ Vt, const float* __restrict__ colbias,
    const int* __restrict__ nearest, unsigned short* __restrict__ AO) {
  __shared__ unsigned short Ks[64 * 72];     // [key][d]
  __shared__ unsigned short Vs[64 * 72];     // [d][key]
  __shared__ unsigned short Ps[4][32 * 72];  // per-wave [q][key]
  __shared__ float Cb[1024];
  int tid = threadIdx.x, wid = tid >> 6, lane = tid & 63;
  int c = lane & 15, quad = lane >> 4;
  int bh = blockIdx.x, qt = blockIdx.y;
  int b = bh >> 4, head = bh & 15;
  int q0 = qt * 128, wq = wid * 32;
  const unsigned short* Qg = Q  + (size_t)(bh * 1024 + q0 + wq) * 64;
  const unsigned short* Kg = K  + (size_t)bh * 1024 * 64;
  const unsigned short* Vg = Vt + (size_t)bh * 64 * 1024;

  *(float4*)&Cb[tid * 4] = *(const float4*)&colbias[b * 1024 + tid * 4];

  s16x8 qf[2][2];
#pragma unroll
  for (int nt = 0; nt < 2; nt++)
#pragma unroll
    for (int ks = 0; ks < 2; ks++)
      qf[nt][ks] = *(const s16x8*)&Qg[(nt * 16 + c) * 64 + ks * 32 + quad * 8];

  int nq[2];
  nq[0] = nearest[b * 1024 + q0 + wq + c];
  nq[1] = nearest[b * 1024 + q0 + wq + 16 + c];

  f32x4 o[2][4];
#pragma unroll
  for (int i = 0; i < 2; i++)
#pragma unroll
    for (int j = 0; j < 4; j++) o[i][j] = (f32x4){0.f, 0.f, 0.f, 0.f};
  float lrun[2] = {0.f, 0.f};

  int srow = tid >> 3, scol8 = (tid & 7) * 8;

  u16x8 kr[2], vr[2];
#pragma unroll
  for (int it = 0; it < 2; ++it) {
    int r2 = it * 32 + srow;
    kr[it] = *(const u16x8*)&Kg[r2 * 64 + scol8];
    vr[it] = *(const u16x8*)&Vg[r2 * 1024 + scol8];
  }
  __syncthreads();   // Cb visible before first use

  for (int kc = 0; kc < 16; ++kc) {
#pragma unroll
    for (int it = 0; it < 2; ++it) {
      int r2 = it * 32 + srow;
      *(u16x8*)&Ks[r2 * 72 + scol8] = kr[it];
      *(u16x8*)&Vs[r2 * 72 + scol8] = vr[it];
    }
    __syncthreads();
    if (kc < 15) {
#pragma unroll
      for (int it = 0; it < 2; ++it) {
        int r2 = it * 32 + srow;
        kr[it] = *(const u16x8*)&Kg[((kc + 1) * 64 + r2) * 64 + scol8];
        vr[it] = *(const u16x8*)&Vg[r2 * 1024 + (kc + 1) * 64 + scol8];
      }
    }

    // S^T = K . Q^T : st[mt][nt] (key = mt*16+quad*4+r, q = nt*16+c)
    f32x4 st[4][2];
#pragma unroll
    for (int mt = 0; mt < 4; mt++)
#pragma unroll
      for (int nt = 0; nt < 2; nt++) st[mt][nt] = (f32x4){0.f, 0.f, 0.f, 0.f};
#pragma unroll
    for (int mt = 0; mt < 4; mt++)
#pragma unroll
      for (int ks = 0; ks < 2; ks++) {
        s16x8 a = *(const s16x8*)&Ks[(mt * 16 + c) * 72 + ks * 32 + quad * 8];
#pragma unroll
        for (int nt = 0; nt < 2; nt++)
          st[mt][nt] = __builtin_amdgcn_mfma_f32_16x16x32_bf16(a, qf[nt][ks], st[mt][nt], 0, 0, 0);
      }

    // rare verb-bias fixup: nq lands in this chunk for at most one element
    bool h0 = (nq[0] >> 6) == kc;
    bool h1 = (nq[1] >> 6) == kc;
    if (__any(h0 || h1)) {
#pragma unroll
      for (int mt = 0; mt < 4; mt++)
#pragma unroll
        for (int nt = 0; nt < 2; nt++)
#pragma unroll
          for (int r = 0; r < 4; r++)
            if (kc * 64 + mt * 16 + quad * 4 + r == nq[nt]) st[mt][nt][r] += VERB2;
    }

    // hot path: cb add + exp2 + v_perm truncate-pack; l from packed values
#pragma unroll
    for (int mt = 0; mt < 4; mt++) {
      f32x4 cb = *(const f32x4*)&Cb[kc * 64 + mt * 16 + quad * 4];
#pragma unroll
      for (int nt = 0; nt < 2; nt++) {
        float e0 = EXP2F(st[mt][nt][0] + cb[0]);
        float e1 = EXP2F(st[mt][nt][1] + cb[1]);
        float e2 = EXP2F(st[mt][nt][2] + cb[2]);
        float e3 = EXP2F(st[mt][nt][3] + cb[3]);
        unsigned p01 = __builtin_amdgcn_perm(__float_as_uint(e1), __float_as_uint(e0), 0x07060302u);
        unsigned p23 = __builtin_amdgcn_perm(__float_as_uint(e3), __float_as_uint(e2), 0x07060302u);
        lrun[nt] += __uint_as_float(p01 << 16) + __uint_as_float(p01 & 0xffff0000u)
                  + __uint_as_float(p23 << 16) + __uint_as_float(p23 & 0xffff0000u);
        uint2 pk; pk.x = p01; pk.y = p23;
        *(uint2*)&Ps[wid][(nt * 16 + c) * 72 + mt * 16 + quad * 4] = pk;
      }
    }
    __asm__ volatile("s_waitcnt lgkmcnt(0)" ::: "memory");

    // O += (P . V) computed SWAPPED: o[mtq][ntd] rows = d, cols = q
#pragma unroll
    for (int ks = 0; ks < 2; ks++) {
      s16x8 pa[2];
#pragma unroll
      for (int mtq = 0; mtq < 2; mtq++)
        pa[mtq] = *(const s16x8*)&Ps[wid][(mtq * 16 + c) * 72 + ks * 32 + quad * 8];
#pragma unroll
      for (int ntd = 0; ntd < 4; ntd++) {
        s16x8 vb = *(const s16x8*)&Vs[(ntd * 16 + c) * 72 + ks * 32 + quad * 8];
#pragma unroll
        for (int mtq = 0; mtq < 2; mtq++)
          o[mtq][ntd] = __builtin_amdgcn_mfma_f32_16x16x32_bf16(vb, pa[mtq], o[mtq][ntd], 0, 0, 0);
      }
    }
    __syncthreads();
  }

  // l-reduction across quads; lane's own token = mtq*16+c -> no shuffle
#pragma unroll
  for (int nt = 0; nt < 2; nt++) {
    lrun[nt] += __shfl_xor(lrun[nt], 16, 64);
    lrun[nt] += __shfl_xor(lrun[nt], 32, 64);
  }
  float linv[2] = {1.0f / lrun[0], 1.0f / lrun[1]};
#pragma unroll
  for (int mtq = 0; mtq < 2; mtq++) {
    size_t row = (size_t)(b * 1024 + q0 + wq + mtq * 16 + c);
#pragma unroll
    for (int ntd = 0; ntd < 4; ntd++) {
      int d0 = ntd * 16 + quad * 4;
      u16x4 pk;
#pragma unroll
      for (int r = 0; r < 4; r++) pk[r] = f2bf(o[mtq][ntd][r] * linv[mtq]);
      *(u16x4*)&AO[row * 1024 + head * 64 + d0] = pk;
    }
  }
}

// ---------------------------------------------------------------------------
extern "C" void kernel_launch(void* const* d_in, const int* in_sizes, int n_in,
                              void* d_out, int out_size, void* d_ws, size_t ws_size,
                              hipStream_t stream) {
  const float* hs     = (const float*)d_in[0];
  const int*   morpho = (const int*)d_in[1];
  const float* Wq = (const float*)d_in[2];
  const float* bq = (const float*)d_in[3];
  const float* Wk = (const float*)d_in[4];
  const float* bk = (const float*)d_in[5];
  const float* Wv = (const float*)d_in[6];
  const float* bv = (const float*)d_in[7];
  const float* Wo = (const float*)d_in[8];
  const float* bo = (const float*)d_in[9];
  float* out = (float*)d_out;

  char* ws = (char*)d_ws;
  unsigned short* hsb = (unsigned short*)(ws);                    // 8 MB [4096][1024]
  unsigned short* Wt  = (unsigned short*)(ws + (8u << 20));       // 8 MB [4][1024][1024]
  unsigned short* Qb  = (unsigned short*)(ws + (16u << 20));      // Q +16MB, K +24MB
  unsigned short* Kb  = (unsigned short*)(ws + (24u << 20));
  unsigned short* Vtb = (unsigned short*)(ws + (40u << 20));      // 8 MB [B,NH,HD,S]
  float* colbias      = (float*)(ws + (48u << 20));               // 16 KB
  int*   nearestp     = (int*)(ws + (48u << 20) + (16u << 10));   // 16 KB
  unsigned short* AO  = hsb;  // reuse: hs_bf16 dead after QKV GEMM

  k_prep<<<3088, 256, 0, stream>>>(hs, hsb, Wq, Wk, Wv, Wo, Wt, morpho,
                                   colbias, nearestp);
  k_qkv<<<dim3(24, 16), 512, 0, stream>>>(hsb, Wt, bq, bk, bv, Qb, Vtb);
  k_attn<<<dim3(64, 8), 256, 0, stream>>>(Qb, Kb, Vtb, colbias, nearestp, AO);
  k_gemm<1><<<dim3(8, 64), 256, 0, stream>>>(AO, Wt + 3 * 1048576, bo, nullptr, nullptr,
                                             nullptr, nullptr, out);
  (void)in_sizes; (void)n_in; (void)out_size; (void)ws_size; (void)Kb;
}